// Round 3
// baseline (841.020 us; speedup 1.0000x reference)
//
#include <hip/hip_runtime.h>
#include <math.h>

// Problem constants (from reference): F_in=256, H=4, HID=64 -> D1=256, OUT=32
#define FIN  256
#define D1   256
#define NHEAD 4
#define HIDC 64
#define DOUT 32
#define NSLOPE 0.2f

__device__ __forceinline__ float lrelu(float x) { return x >= 0.f ? x : NSLOPE * x; }

// ---------------- CSR construction ----------------
__global__ void zero2_kernel(int* __restrict__ a, int* __restrict__ b, int n) {
  int i = blockIdx.x * blockDim.x + threadIdx.x;
  if (i < n) { a[i] = 0; b[i] = 0; }
}

__global__ void count_kernel(const int* __restrict__ src, const int* __restrict__ dst,
                             int* __restrict__ deg, int E, int N) {
  int i = blockIdx.x * blockDim.x + threadIdx.x;
  if (i < E) {
    atomicAdd(&deg[dst[i]], 1);
  } else if (i < E + N) {
    atomicAdd(&deg[i - E], 1);   // self-loop
  }
}

__global__ __launch_bounds__(1024) void scan_kernel(const int* __restrict__ deg,
                                                    int* __restrict__ row_ptr, int N) {
  __shared__ int sh[1024];
  int t = threadIdx.x;
  int chunk = (N + 1023) / 1024;
  int b = t * chunk;
  int e = min(b + chunk, N);
  int s = 0;
  for (int i = b; i < e; ++i) s += deg[i];
  sh[t] = s;
  __syncthreads();
  // Hillis-Steele inclusive scan over 1024 partials
  for (int off = 1; off < 1024; off <<= 1) {
    int v = sh[t];
    int u = (t >= off) ? sh[t - off] : 0;
    __syncthreads();
    sh[t] = v + u;
    __syncthreads();
  }
  int run = sh[t] - s;   // exclusive prefix of this chunk
  for (int i = b; i < e; ++i) { run += deg[i]; row_ptr[i + 1] = run; }
  if (t == 0) row_ptr[0] = 0;
}

__global__ void scatter_kernel(const int* __restrict__ src, const int* __restrict__ dst,
                               const int* __restrict__ row_ptr, int* __restrict__ cur,
                               int* __restrict__ col, int E, int N) {
  int i = blockIdx.x * blockDim.x + threadIdx.x;
  int s, d;
  if (i < E) { s = src[i]; d = dst[i]; }
  else if (i < E + N) { s = i - E; d = i - E; }
  else return;
  int pos = row_ptr[d] + atomicAdd(&cur[d], 1);
  col[pos] = s;
}

// ---------------- GEMM1: [N,256] @ [256,256] -> [N,256] ----------------
__global__ __launch_bounds__(256) void gemm1_kernel(const float* __restrict__ A,
                                                    const float* __restrict__ B,
                                                    float* __restrict__ C, int N) {
  __shared__ float xs[32][68];   // transposed A tile: xs[k][r]
  __shared__ float ws[32][68];   // B tile: ws[k][c]
  int t = threadIdx.x;
  int tx = t & 15, ty = t >> 4;
  int row0 = blockIdx.x * 64;
  int col0 = blockIdx.y * 64;
  float acc[4][4] = {};
  for (int k0 = 0; k0 < 256; k0 += 32) {
    // stage A tile (64 rows x 32 k), transposed
#pragma unroll
    for (int rep = 0; rep < 2; ++rep) {
      int r = (t >> 3) + rep * 32;
      int kk = (t & 7) * 4;
      int gr = row0 + r;
      float4 v = {0.f, 0.f, 0.f, 0.f};
      if (gr < N) v = *(const float4*)&A[(size_t)gr * FIN + k0 + kk];
      xs[kk + 0][r] = v.x; xs[kk + 1][r] = v.y; xs[kk + 2][r] = v.z; xs[kk + 3][r] = v.w;
    }
    // stage B tile (32 k x 64 cols)
#pragma unroll
    for (int rep = 0; rep < 2; ++rep) {
      int kk = (t >> 4) + rep * 16;
      int cc = (t & 15) * 4;
      float4 v = *(const float4*)&B[(size_t)(k0 + kk) * D1 + col0 + cc];
      *(float4*)&ws[kk][cc] = v;
    }
    __syncthreads();
#pragma unroll
    for (int k = 0; k < 32; ++k) {
      float4 av = *(const float4*)&xs[k][ty * 4];
      float4 bv = *(const float4*)&ws[k][tx * 4];
      float a_[4] = {av.x, av.y, av.z, av.w};
      float b_[4] = {bv.x, bv.y, bv.z, bv.w};
#pragma unroll
      for (int i = 0; i < 4; ++i)
#pragma unroll
        for (int j = 0; j < 4; ++j)
          acc[i][j] = fmaf(a_[i], b_[j], acc[i][j]);
    }
    __syncthreads();
  }
#pragma unroll
  for (int i = 0; i < 4; ++i) {
    int gr = row0 + ty * 4 + i;
    if (gr < N) {
      float4 o = {acc[i][0], acc[i][1], acc[i][2], acc[i][3]};
      *(float4*)&C[(size_t)gr * D1 + col0 + tx * 4] = o;
    }
  }
}

// ---------------- alpha1: per-node dot with att vectors ----------------
// Flat layout identity: channel lane*4 corresponds to head (lane>>4), and the
// flattened [H][C] attention vector index is also just lane*4.
__global__ __launch_bounds__(256) void alpha1_kernel(const float* __restrict__ h,
                                                     const float* __restrict__ a_src,
                                                     const float* __restrict__ a_dst,
                                                     float* __restrict__ as,
                                                     float* __restrict__ ad, int N) {
  int wid = (blockIdx.x * blockDim.x + threadIdx.x) >> 6;
  if (wid >= N) return;
  int lane = threadIdx.x & 63;
  float4 v  = *(const float4*)&h[(size_t)wid * D1 + lane * 4];
  float4 s4 = *(const float4*)&a_src[lane * 4];
  float4 d4 = *(const float4*)&a_dst[lane * 4];
  float ps = v.x * s4.x + v.y * s4.y + v.z * s4.z + v.w * s4.w;
  float pd = v.x * d4.x + v.y * d4.y + v.z * d4.z + v.w * d4.w;
#pragma unroll
  for (int off = 8; off >= 1; off >>= 1) {
    ps += __shfl_xor(ps, off);
    pd += __shfl_xor(pd, off);
  }
  int hh = lane >> 4;
  if ((lane & 15) == 0) { as[wid * 4 + hh] = ps; ad[wid * 4 + hh] = pd; }
}

// ---------------- agg1: segment softmax + aggregate, one wave per node ----------------
// All lanes redundantly compute per-node per-head softmax stats via uniform
// broadcast loops (no shuffles, no degree cap). Then each lane aggregates its
// own 4 channels.
__global__ __launch_bounds__(256) void agg1_kernel(const float* __restrict__ hl,
                                                   const float* __restrict__ as1,
                                                   const float* __restrict__ ad1,
                                                   const int* __restrict__ row_ptr,
                                                   const int* __restrict__ col,
                                                   const float* __restrict__ b1,
                                                   float* __restrict__ h1, int N) {
  int wid = (blockIdx.x * blockDim.x + threadIdx.x) >> 6;
  if (wid >= N) return;
  int lane = threadIdx.x & 63;
  int beg = row_ptr[wid], end = row_ptr[wid + 1];
  int deg = end - beg;
  float4 adv = *(const float4*)&ad1[wid * 4];
  float ad[4] = {adv.x, adv.y, adv.z, adv.w};

  float mx[4] = {-INFINITY, -INFINITY, -INFINITY, -INFINITY};
  for (int j = 0; j < deg; ++j) {
    int s = col[beg + j];                              // uniform -> broadcast
    float4 av = *(const float4*)&as1[(size_t)s * 4];   // uniform -> broadcast
    mx[0] = fmaxf(mx[0], lrelu(av.x + ad[0]));
    mx[1] = fmaxf(mx[1], lrelu(av.y + ad[1]));
    mx[2] = fmaxf(mx[2], lrelu(av.z + ad[2]));
    mx[3] = fmaxf(mx[3], lrelu(av.w + ad[3]));
  }
  float sm[4] = {0.f, 0.f, 0.f, 0.f};
  for (int j = 0; j < deg; ++j) {
    int s = col[beg + j];
    float4 av = *(const float4*)&as1[(size_t)s * 4];
    sm[0] += expf(lrelu(av.x + ad[0]) - mx[0]);
    sm[1] += expf(lrelu(av.y + ad[1]) - mx[1]);
    sm[2] += expf(lrelu(av.z + ad[2]) - mx[2]);
    sm[3] += expf(lrelu(av.w + ad[3]) - mx[3]);
  }
  float inv[4];
#pragma unroll
  for (int h = 0; h < 4; ++h) inv[h] = 1.0f / (sm[h] + 1e-16f);

  // aggregate: lane owns flat channels [lane*4, lane*4+3], head = lane>>4
  int hm = lane >> 4;
  float adh = ad[hm], mh = mx[hm], ih = inv[hm];
  float4 acc = {0.f, 0.f, 0.f, 0.f};
  for (int j = 0; j < deg; ++j) {
    int s = col[beg + j];                              // uniform -> broadcast
    float e = lrelu(as1[(size_t)s * 4 + hm] + adh);
    float w = expf(e - mh) * ih;
    float4 v = *(const float4*)&hl[(size_t)s * D1 + lane * 4];
    acc.x = fmaf(w, v.x, acc.x);
    acc.y = fmaf(w, v.y, acc.y);
    acc.z = fmaf(w, v.z, acc.z);
    acc.w = fmaf(w, v.w, acc.w);
  }
  float4 bb = *(const float4*)&b1[lane * 4];
  float4 o;
  o.x = fmaxf(acc.x + bb.x, 0.f);
  o.y = fmaxf(acc.y + bb.y, 0.f);
  o.z = fmaxf(acc.z + bb.z, 0.f);
  o.w = fmaxf(acc.w + bb.w, 0.f);
  *(float4*)&h1[(size_t)wid * D1 + lane * 4] = o;
}

// ---------------- GEMM2: [N,256] @ [256,32] -> [N,32] ----------------
__global__ __launch_bounds__(256) void gemm2_kernel(const float* __restrict__ A,
                                                    const float* __restrict__ B,
                                                    float* __restrict__ C, int N) {
  __shared__ float ws[256][33];   // full W2
  __shared__ float xs[32][132];   // transposed A chunk
  int t = threadIdx.x;
  // stage full W2, coalesced
#pragma unroll
  for (int j = 0; j < 32; ++j) {
    int idx = j * 256 + t;
    ws[idx >> 5][idx & 31] = B[idx];
  }
  int row0 = blockIdx.x * 128;
  int tx = t & 31, ty = t >> 5;
  float acc[16] = {};
  for (int k0 = 0; k0 < 256; k0 += 32) {
    __syncthreads();
#pragma unroll
    for (int rep = 0; rep < 4; ++rep) {
      int r = (t >> 3) + rep * 32;
      int kk = (t & 7) * 4;
      int gr = row0 + r;
      float4 v = {0.f, 0.f, 0.f, 0.f};
      if (gr < N) v = *(const float4*)&A[(size_t)gr * D1 + k0 + kk];
      xs[kk + 0][r] = v.x; xs[kk + 1][r] = v.y; xs[kk + 2][r] = v.z; xs[kk + 3][r] = v.w;
    }
    __syncthreads();
#pragma unroll
    for (int k = 0; k < 32; ++k) {
      float w = ws[k0 + k][tx];
#pragma unroll
      for (int rq = 0; rq < 4; ++rq) {
        float4 a4 = *(const float4*)&xs[k][ty * 16 + rq * 4];
        acc[rq * 4 + 0] = fmaf(a4.x, w, acc[rq * 4 + 0]);
        acc[rq * 4 + 1] = fmaf(a4.y, w, acc[rq * 4 + 1]);
        acc[rq * 4 + 2] = fmaf(a4.z, w, acc[rq * 4 + 2]);
        acc[rq * 4 + 3] = fmaf(a4.w, w, acc[rq * 4 + 3]);
      }
    }
  }
#pragma unroll
  for (int j = 0; j < 16; ++j) {
    int gr = row0 + ty * 16 + j;
    if (gr < N) C[(size_t)gr * DOUT + tx] = acc[j];
  }
}

// ---------------- alpha2: one wave handles two nodes ----------------
__global__ __launch_bounds__(256) void alpha2_kernel(const float* __restrict__ h2,
                                                     const float* __restrict__ a_src,
                                                     const float* __restrict__ a_dst,
                                                     float* __restrict__ as,
                                                     float* __restrict__ ad, int N) {
  int wid = (blockIdx.x * blockDim.x + threadIdx.x) >> 6;
  int lane = threadIdx.x & 63;
  int n = wid * 2 + (lane >> 5);
  int c = lane & 31;
  float v = (n < N) ? h2[(size_t)n * DOUT + c] : 0.f;
  float ps = v * a_src[c];
  float pd = v * a_dst[c];
#pragma unroll
  for (int off = 16; off >= 1; off >>= 1) {
    ps += __shfl_xor(ps, off);
    pd += __shfl_xor(pd, off);
  }
  if (c == 0 && n < N) { as[n] = ps; ad[n] = pd; }
}

// ---------------- agg2: segment softmax + aggregate (H=1, C=32) ----------------
// Fully uniform loops; lanes 0-31 and 32-63 redundantly compute the same
// channel sums; lanes 0-31 write.
__global__ __launch_bounds__(256) void agg2_kernel(const float* __restrict__ h2,
                                                   const float* __restrict__ as2,
                                                   const float* __restrict__ ad2,
                                                   const int* __restrict__ row_ptr,
                                                   const int* __restrict__ col,
                                                   const float* __restrict__ b2,
                                                   float* __restrict__ out, int N) {
  int wid = (blockIdx.x * blockDim.x + threadIdx.x) >> 6;
  if (wid >= N) return;
  int lane = threadIdx.x & 63;
  int beg = row_ptr[wid], end = row_ptr[wid + 1];
  int deg = end - beg;
  float ad = ad2[wid];

  float mx = -INFINITY;
  for (int j = 0; j < deg; ++j) {
    float a = as2[col[beg + j]];
    mx = fmaxf(mx, lrelu(a + ad));
  }
  float sm = 0.f;
  for (int j = 0; j < deg; ++j) {
    float a = as2[col[beg + j]];
    sm += expf(lrelu(a + ad) - mx);
  }
  float inv = 1.0f / (sm + 1e-16f);

  int c = lane & 31;
  float acc = 0.f;
  for (int j = 0; j < deg; ++j) {
    int s = col[beg + j];
    float a = as2[s];
    float w = expf(lrelu(a + ad) - mx) * inv;
    acc = fmaf(w, h2[(size_t)s * DOUT + c], acc);
  }
  if (lane < 32) out[(size_t)wid * DOUT + c] = acc + b2[c];
}

// ---------------- launch ----------------
extern "C" void kernel_launch(void* const* d_in, const int* in_sizes, int n_in,
                              void* d_out, int out_size, void* d_ws, size_t ws_size,
                              hipStream_t stream) {
  const float* x     = (const float*)d_in[0];
  const int*   ei    = (const int*)d_in[1];
  const float* W1    = (const float*)d_in[2];
  const float* asrc1 = (const float*)d_in[3];
  const float* adst1 = (const float*)d_in[4];
  const float* b1    = (const float*)d_in[5];
  const float* W2    = (const float*)d_in[6];
  const float* asrc2 = (const float*)d_in[7];
  const float* adst2 = (const float*)d_in[8];
  const float* b2    = (const float*)d_in[9];

  const int N = in_sizes[0] / FIN;
  const int E = in_sizes[1] / 2;
  const int ET = E + N;
  const int* src = ei;
  const int* dst = ei + E;

  char* base = (char*)d_ws;
  size_t off = 0;
  auto alloc = [&](size_t bytes) -> void* {
    void* p = base + off;
    off = (off + bytes + 255) & ~(size_t)255;
    return p;
  };
  // small arrays first
  int* row_ptr = (int*)alloc((size_t)(N + 1) * 4);
  int* deg     = (int*)alloc((size_t)N * 4);
  int* cur     = (int*)alloc((size_t)N * 4);
  int* col     = (int*)alloc((size_t)ET * 4);
  float* as1   = (float*)alloc((size_t)N * 4 * 4);
  float* ad1   = (float*)alloc((size_t)N * 4 * 4);
  float* as2   = (float*)alloc((size_t)N * 4);
  float* ad2   = (float*)alloc((size_t)N * 4);
  float* hl1   = (float*)alloc((size_t)N * D1 * 4);
  float* h1    = (float*)alloc((size_t)N * D1 * 4);
  float* h2    = hl1;   // reuse: hl1 dead after agg1
  float* out   = (float*)d_out;

  // CSR build (shared by both layers)
  hipLaunchKernelGGL(zero2_kernel, dim3((N + 255) / 256), dim3(256), 0, stream, deg, cur, N);
  hipLaunchKernelGGL(count_kernel, dim3((ET + 255) / 256), dim3(256), 0, stream, src, dst, deg, E, N);
  hipLaunchKernelGGL(scan_kernel, dim3(1), dim3(1024), 0, stream, deg, row_ptr, N);
  hipLaunchKernelGGL(scatter_kernel, dim3((ET + 255) / 256), dim3(256), 0, stream, src, dst, row_ptr, cur, col, E, N);

  // layer 1
  hipLaunchKernelGGL(gemm1_kernel, dim3((N + 63) / 64, 4), dim3(256), 0, stream, x, W1, hl1, N);
  hipLaunchKernelGGL(alpha1_kernel, dim3((N + 3) / 4), dim3(256), 0, stream, hl1, asrc1, adst1, as1, ad1, N);
  hipLaunchKernelGGL(agg1_kernel, dim3((N + 3) / 4), dim3(256), 0, stream, hl1, as1, ad1, row_ptr, col, b1, h1, N);

  // layer 2
  hipLaunchKernelGGL(gemm2_kernel, dim3((N + 127) / 128), dim3(256), 0, stream, h1, W2, h2, N);
  hipLaunchKernelGGL(alpha2_kernel, dim3((N + 7) / 8), dim3(256), 0, stream, h2, asrc2, adst2, as2, ad2, N);
  hipLaunchKernelGGL(agg2_kernel, dim3((N + 3) / 4), dim3(256), 0, stream, h2, as2, ad2, row_ptr, col, b2, out, N);
}

// Round 6
// 582.831 us; speedup vs baseline: 1.4430x; 1.4430x over previous
//
#include <hip/hip_runtime.h>
#include <math.h>

// Problem constants (from reference): F_in=256, H=4, HID=64 -> D1=256, OUT=32
#define FIN  256
#define D1   256
#define NHEAD 4
#define HIDC 64
#define DOUT 32
#define NSLOPE 0.2f

__device__ __forceinline__ float lrelu(float x) { return x >= 0.f ? x : NSLOPE * x; }

// ---------------- CSR construction ----------------
__global__ void zero2_kernel(int* __restrict__ a, int* __restrict__ b, int n) {
  int i = blockIdx.x * blockDim.x + threadIdx.x;
  if (i < n) { a[i] = 0; b[i] = 0; }
}

__global__ void count_kernel(const int* __restrict__ src, const int* __restrict__ dst,
                             int* __restrict__ deg, int E, int N) {
  int i = blockIdx.x * blockDim.x + threadIdx.x;
  if (i < E) {
    atomicAdd(&deg[dst[i]], 1);
  } else if (i < E + N) {
    atomicAdd(&deg[i - E], 1);   // self-loop
  }
}

__global__ __launch_bounds__(1024) void scan_kernel(const int* __restrict__ deg,
                                                    int* __restrict__ row_ptr, int N) {
  __shared__ int sh[1024];
  int t = threadIdx.x;
  int chunk = (N + 1023) / 1024;
  int b = t * chunk;
  int e = min(b + chunk, N);
  int s = 0;
  for (int i = b; i < e; ++i) s += deg[i];
  sh[t] = s;
  __syncthreads();
  // Hillis-Steele inclusive scan over 1024 partials
  for (int off = 1; off < 1024; off <<= 1) {
    int v = sh[t];
    int u = (t >= off) ? sh[t - off] : 0;
    __syncthreads();
    sh[t] = v + u;
    __syncthreads();
  }
  int run = sh[t] - s;   // exclusive prefix of this chunk
  for (int i = b; i < e; ++i) { run += deg[i]; row_ptr[i + 1] = run; }
  if (t == 0) row_ptr[0] = 0;
}

__global__ void scatter_kernel(const int* __restrict__ src, const int* __restrict__ dst,
                               const int* __restrict__ row_ptr, int* __restrict__ cur,
                               int* __restrict__ col, int E, int N) {
  int i = blockIdx.x * blockDim.x + threadIdx.x;
  int s, d;
  if (i < E) { s = src[i]; d = dst[i]; }
  else if (i < E + N) { s = i - E; d = i - E; }
  else return;
  int pos = row_ptr[d] + atomicAdd(&cur[d], 1);
  col[pos] = s;
}

// ---------------- GEMM1: [N,256] @ [256,256] -> [N,256] ----------------
__global__ __launch_bounds__(256) void gemm1_kernel(const float* __restrict__ A,
                                                    const float* __restrict__ B,
                                                    float* __restrict__ C, int N) {
  __shared__ float xs[32][68];   // transposed A tile: xs[k][r]
  __shared__ float ws[32][68];   // B tile: ws[k][c]
  int t = threadIdx.x;
  int tx = t & 15, ty = t >> 4;
  int row0 = blockIdx.x * 64;
  int col0 = blockIdx.y * 64;
  float acc[4][4] = {};
  for (int k0 = 0; k0 < 256; k0 += 32) {
    // stage A tile (64 rows x 32 k), transposed
#pragma unroll
    for (int rep = 0; rep < 2; ++rep) {
      int r = (t >> 3) + rep * 32;
      int kk = (t & 7) * 4;
      int gr = row0 + r;
      float4 v = {0.f, 0.f, 0.f, 0.f};
      if (gr < N) v = *(const float4*)&A[(size_t)gr * FIN + k0 + kk];
      xs[kk + 0][r] = v.x; xs[kk + 1][r] = v.y; xs[kk + 2][r] = v.z; xs[kk + 3][r] = v.w;
    }
    // stage B tile (32 k x 64 cols)
#pragma unroll
    for (int rep = 0; rep < 2; ++rep) {
      int kk = (t >> 4) + rep * 16;
      int cc = (t & 15) * 4;
      float4 v = *(const float4*)&B[(size_t)(k0 + kk) * D1 + col0 + cc];
      *(float4*)&ws[kk][cc] = v;
    }
    __syncthreads();
#pragma unroll
    for (int k = 0; k < 32; ++k) {
      float4 av = *(const float4*)&xs[k][ty * 4];
      float4 bv = *(const float4*)&ws[k][tx * 4];
      float a_[4] = {av.x, av.y, av.z, av.w};
      float b_[4] = {bv.x, bv.y, bv.z, bv.w};
#pragma unroll
      for (int i = 0; i < 4; ++i)
#pragma unroll
        for (int j = 0; j < 4; ++j)
          acc[i][j] = fmaf(a_[i], b_[j], acc[i][j]);
    }
    __syncthreads();
  }
#pragma unroll
  for (int i = 0; i < 4; ++i) {
    int gr = row0 + ty * 4 + i;
    if (gr < N) {
      float4 o = {acc[i][0], acc[i][1], acc[i][2], acc[i][3]};
      *(float4*)&C[(size_t)gr * D1 + col0 + tx * 4] = o;
    }
  }
}

// ---------------- alpha1: per-node dot with att vectors ----------------
__global__ __launch_bounds__(256) void alpha1_kernel(const float* __restrict__ h,
                                                     const float* __restrict__ a_src,
                                                     const float* __restrict__ a_dst,
                                                     float* __restrict__ as,
                                                     float* __restrict__ ad, int N) {
  int wid = (blockIdx.x * blockDim.x + threadIdx.x) >> 6;
  if (wid >= N) return;
  int lane = threadIdx.x & 63;
  float4 v  = *(const float4*)&h[(size_t)wid * D1 + lane * 4];
  float4 s4 = *(const float4*)&a_src[lane * 4];
  float4 d4 = *(const float4*)&a_dst[lane * 4];
  float ps = v.x * s4.x + v.y * s4.y + v.z * s4.z + v.w * s4.w;
  float pd = v.x * d4.x + v.y * d4.y + v.z * d4.z + v.w * d4.w;
#pragma unroll
  for (int off = 8; off >= 1; off >>= 1) {
    ps += __shfl_xor(ps, off);
    pd += __shfl_xor(pd, off);
  }
  int hh = lane >> 4;
  if ((lane & 15) == 0) { as[wid * 4 + hh] = ps; ad[wid * 4 + hh] = pd; }
}

// ---------------- stats1: per-(node,head) online softmax stats ----------------
// One thread per (node,head); 200K threads give deep TLP to hide the serial
// dependent gather chain. Branchless online max/sum with col prefetch.
__global__ __launch_bounds__(256) void stats1_kernel(const float* __restrict__ as1,
                                                     const float* __restrict__ ad1,
                                                     const int* __restrict__ row_ptr,
                                                     const int* __restrict__ col,
                                                     float* __restrict__ mx1,
                                                     float* __restrict__ inv1, int N) {
  int t = blockIdx.x * blockDim.x + threadIdx.x;
  if (t >= N * 4) return;
  int n = t >> 2, h = t & 3;
  int beg = row_ptr[n];
  int deg = row_ptr[n + 1] - beg;
  float adh = ad1[t];
  float m = -INFINITY, s = 0.f;
  int cn = col[beg];
  for (int j = 0; j < deg; ++j) {
    int c = cn;
    if (j + 1 < deg) cn = col[beg + j + 1];      // prefetch next col
    float e = lrelu(as1[(size_t)c * 4 + h] + adh);
    float nm = fmaxf(m, e);
    s = s * expf(m - nm) + expf(e - nm);         // expf(-inf)=0 first iter
    m = nm;
  }
  mx1[t] = m;
  inv1[t] = 1.f / (s + 1e-16f);
}

// ---------------- agg1: weighted aggregate, 4-deep independent loads ----------------
// One wave per node; lane owns flat channels [lane*4,lane*4+4), head hm=lane>>4.
// All addressing is plain loads (uniform or quarter-uniform -> HW broadcast);
// 4 edges in flight per iteration (4 col + 4 as1 + 4 hl1 rows).
__global__ __launch_bounds__(256) void agg1_kernel(const float* __restrict__ hl,
                                                   const float* __restrict__ as1,
                                                   const float* __restrict__ ad1,
                                                   const float* __restrict__ mx1,
                                                   const float* __restrict__ inv1,
                                                   const int* __restrict__ row_ptr,
                                                   const int* __restrict__ col,
                                                   const float* __restrict__ b1,
                                                   float* __restrict__ h1, int N) {
  int wid = (blockIdx.x * blockDim.x + threadIdx.x) >> 6;
  if (wid >= N) return;
  int lane = threadIdx.x & 63;
  int hm = lane >> 4;
  int beg = row_ptr[wid];
  int deg = row_ptr[wid + 1] - beg;
  float adh = ad1[wid * 4 + hm];
  float mh  = mx1[wid * 4 + hm];
  float ih  = inv1[wid * 4 + hm];
  float4 acc = {0.f, 0.f, 0.f, 0.f};
  int j = 0;
  for (; j + 4 <= deg; j += 4) {
    int s0 = col[beg + j + 0];
    int s1 = col[beg + j + 1];
    int s2 = col[beg + j + 2];
    int s3 = col[beg + j + 3];
    float a0 = as1[(size_t)s0 * 4 + hm];
    float a1 = as1[(size_t)s1 * 4 + hm];
    float a2 = as1[(size_t)s2 * 4 + hm];
    float a3 = as1[(size_t)s3 * 4 + hm];
    float4 v0 = *(const float4*)&hl[(size_t)s0 * D1 + lane * 4];
    float4 v1 = *(const float4*)&hl[(size_t)s1 * D1 + lane * 4];
    float4 v2 = *(const float4*)&hl[(size_t)s2 * D1 + lane * 4];
    float4 v3 = *(const float4*)&hl[(size_t)s3 * D1 + lane * 4];
    float w0 = expf(lrelu(a0 + adh) - mh) * ih;
    float w1 = expf(lrelu(a1 + adh) - mh) * ih;
    float w2 = expf(lrelu(a2 + adh) - mh) * ih;
    float w3 = expf(lrelu(a3 + adh) - mh) * ih;
    acc.x = fmaf(w0, v0.x, acc.x); acc.y = fmaf(w0, v0.y, acc.y);
    acc.z = fmaf(w0, v0.z, acc.z); acc.w = fmaf(w0, v0.w, acc.w);
    acc.x = fmaf(w1, v1.x, acc.x); acc.y = fmaf(w1, v1.y, acc.y);
    acc.z = fmaf(w1, v1.z, acc.z); acc.w = fmaf(w1, v1.w, acc.w);
    acc.x = fmaf(w2, v2.x, acc.x); acc.y = fmaf(w2, v2.y, acc.y);
    acc.z = fmaf(w2, v2.z, acc.z); acc.w = fmaf(w2, v2.w, acc.w);
    acc.x = fmaf(w3, v3.x, acc.x); acc.y = fmaf(w3, v3.y, acc.y);
    acc.z = fmaf(w3, v3.z, acc.z); acc.w = fmaf(w3, v3.w, acc.w);
  }
  for (; j < deg; ++j) {
    int s0 = col[beg + j];
    float a0 = as1[(size_t)s0 * 4 + hm];
    float4 v0 = *(const float4*)&hl[(size_t)s0 * D1 + lane * 4];
    float w0 = expf(lrelu(a0 + adh) - mh) * ih;
    acc.x = fmaf(w0, v0.x, acc.x); acc.y = fmaf(w0, v0.y, acc.y);
    acc.z = fmaf(w0, v0.z, acc.z); acc.w = fmaf(w0, v0.w, acc.w);
  }
  float4 bb = *(const float4*)&b1[lane * 4];
  float4 o;
  o.x = fmaxf(acc.x + bb.x, 0.f);
  o.y = fmaxf(acc.y + bb.y, 0.f);
  o.z = fmaxf(acc.z + bb.z, 0.f);
  o.w = fmaxf(acc.w + bb.w, 0.f);
  *(float4*)&h1[(size_t)wid * D1 + lane * 4] = o;
}

// ---------------- GEMM2: [N,256] @ [256,32] -> [N,32] ----------------
__global__ __launch_bounds__(256) void gemm2_kernel(const float* __restrict__ A,
                                                    const float* __restrict__ B,
                                                    float* __restrict__ C, int N) {
  __shared__ float ws[256][33];   // full W2
  __shared__ float xs[32][132];   // transposed A chunk
  int t = threadIdx.x;
#pragma unroll
  for (int j = 0; j < 32; ++j) {
    int idx = j * 256 + t;
    ws[idx >> 5][idx & 31] = B[idx];
  }
  int row0 = blockIdx.x * 128;
  int tx = t & 31, ty = t >> 5;
  float acc[16] = {};
  for (int k0 = 0; k0 < 256; k0 += 32) {
    __syncthreads();
#pragma unroll
    for (int rep = 0; rep < 4; ++rep) {
      int r = (t >> 3) + rep * 32;
      int kk = (t & 7) * 4;
      int gr = row0 + r;
      float4 v = {0.f, 0.f, 0.f, 0.f};
      if (gr < N) v = *(const float4*)&A[(size_t)gr * D1 + k0 + kk];
      xs[kk + 0][r] = v.x; xs[kk + 1][r] = v.y; xs[kk + 2][r] = v.z; xs[kk + 3][r] = v.w;
    }
    __syncthreads();
#pragma unroll
    for (int k = 0; k < 32; ++k) {
      float w = ws[k0 + k][tx];
#pragma unroll
      for (int rq = 0; rq < 4; ++rq) {
        float4 a4 = *(const float4*)&xs[k][ty * 16 + rq * 4];
        acc[rq * 4 + 0] = fmaf(a4.x, w, acc[rq * 4 + 0]);
        acc[rq * 4 + 1] = fmaf(a4.y, w, acc[rq * 4 + 1]);
        acc[rq * 4 + 2] = fmaf(a4.z, w, acc[rq * 4 + 2]);
        acc[rq * 4 + 3] = fmaf(a4.w, w, acc[rq * 4 + 3]);
      }
    }
  }
#pragma unroll
  for (int j = 0; j < 16; ++j) {
    int gr = row0 + ty * 16 + j;
    if (gr < N) C[(size_t)gr * DOUT + tx] = acc[j];
  }
}

// ---------------- alpha2: one wave handles two nodes ----------------
__global__ __launch_bounds__(256) void alpha2_kernel(const float* __restrict__ h2,
                                                     const float* __restrict__ a_src,
                                                     const float* __restrict__ a_dst,
                                                     float* __restrict__ as,
                                                     float* __restrict__ ad, int N) {
  int wid = (blockIdx.x * blockDim.x + threadIdx.x) >> 6;
  int lane = threadIdx.x & 63;
  int n = wid * 2 + (lane >> 5);
  int c = lane & 31;
  float v = (n < N) ? h2[(size_t)n * DOUT + c] : 0.f;
  float ps = v * a_src[c];
  float pd = v * a_dst[c];
#pragma unroll
  for (int off = 16; off >= 1; off >>= 1) {
    ps += __shfl_xor(ps, off);
    pd += __shfl_xor(pd, off);
  }
  if (c == 0 && n < N) { as[n] = ps; ad[n] = pd; }
}

// ---------------- stats2: per-node online softmax stats (H=1) ----------------
__global__ __launch_bounds__(256) void stats2_kernel(const float* __restrict__ as2,
                                                     const float* __restrict__ ad2,
                                                     const int* __restrict__ row_ptr,
                                                     const int* __restrict__ col,
                                                     float* __restrict__ mx2,
                                                     float* __restrict__ inv2, int N) {
  int n = blockIdx.x * blockDim.x + threadIdx.x;
  if (n >= N) return;
  int beg = row_ptr[n];
  int deg = row_ptr[n + 1] - beg;
  float ad = ad2[n];
  float m = -INFINITY, s = 0.f;
  int cn = col[beg];
  for (int j = 0; j < deg; ++j) {
    int c = cn;
    if (j + 1 < deg) cn = col[beg + j + 1];
    float e = lrelu(as2[c] + ad);
    float nm = fmaxf(m, e);
    s = s * expf(m - nm) + expf(e - nm);
    m = nm;
  }
  mx2[n] = m;
  inv2[n] = 1.f / (s + 1e-16f);
}

// ---------------- agg2: weighted aggregate (H=1, C=32), 4-deep loads ----------------
// Both wave halves redundantly compute the same 32 channels; lanes<32 write.
__global__ __launch_bounds__(256) void agg2_kernel(const float* __restrict__ h2,
                                                   const float* __restrict__ as2,
                                                   const float* __restrict__ ad2,
                                                   const float* __restrict__ mx2,
                                                   const float* __restrict__ inv2,
                                                   const int* __restrict__ row_ptr,
                                                   const int* __restrict__ col,
                                                   const float* __restrict__ b2,
                                                   float* __restrict__ out, int N) {
  int wid = (blockIdx.x * blockDim.x + threadIdx.x) >> 6;
  if (wid >= N) return;
  int lane = threadIdx.x & 63;
  int c = lane & 31;
  int beg = row_ptr[wid];
  int deg = row_ptr[wid + 1] - beg;
  float ad = ad2[wid];
  float mh = mx2[wid];
  float ih = inv2[wid];
  float acc = 0.f;
  int j = 0;
  for (; j + 4 <= deg; j += 4) {
    int s0 = col[beg + j + 0];
    int s1 = col[beg + j + 1];
    int s2 = col[beg + j + 2];
    int s3 = col[beg + j + 3];
    float a0 = as2[s0];
    float a1 = as2[s1];
    float a2 = as2[s2];
    float a3 = as2[s3];
    float v0 = h2[(size_t)s0 * DOUT + c];
    float v1 = h2[(size_t)s1 * DOUT + c];
    float v2 = h2[(size_t)s2 * DOUT + c];
    float v3 = h2[(size_t)s3 * DOUT + c];
    float w0 = expf(lrelu(a0 + ad) - mh) * ih;
    float w1 = expf(lrelu(a1 + ad) - mh) * ih;
    float w2 = expf(lrelu(a2 + ad) - mh) * ih;
    float w3 = expf(lrelu(a3 + ad) - mh) * ih;
    acc = fmaf(w0, v0, acc);
    acc = fmaf(w1, v1, acc);
    acc = fmaf(w2, v2, acc);
    acc = fmaf(w3, v3, acc);
  }
  for (; j < deg; ++j) {
    int s0 = col[beg + j];
    float a0 = as2[s0];
    float v0 = h2[(size_t)s0 * DOUT + c];
    float w0 = expf(lrelu(a0 + ad) - mh) * ih;
    acc = fmaf(w0, v0, acc);
  }
  if (lane < 32) out[(size_t)wid * DOUT + c] = acc + b2[c];
}

// ---------------- launch ----------------
extern "C" void kernel_launch(void* const* d_in, const int* in_sizes, int n_in,
                              void* d_out, int out_size, void* d_ws, size_t ws_size,
                              hipStream_t stream) {
  const float* x     = (const float*)d_in[0];
  const int*   ei    = (const int*)d_in[1];
  const float* W1    = (const float*)d_in[2];
  const float* asrc1 = (const float*)d_in[3];
  const float* adst1 = (const float*)d_in[4];
  const float* b1    = (const float*)d_in[5];
  const float* W2    = (const float*)d_in[6];
  const float* asrc2 = (const float*)d_in[7];
  const float* adst2 = (const float*)d_in[8];
  const float* b2    = (const float*)d_in[9];

  const int N = in_sizes[0] / FIN;
  const int E = in_sizes[1] / 2;
  const int ET = E + N;
  const int* src = ei;
  const int* dst = ei + E;

  char* base = (char*)d_ws;
  size_t off = 0;
  auto alloc = [&](size_t bytes) -> void* {
    void* p = base + off;
    off = (off + bytes + 255) & ~(size_t)255;
    return p;
  };
  int* row_ptr = (int*)alloc((size_t)(N + 1) * 4);
  int* deg     = (int*)alloc((size_t)N * 4);
  int* cur     = (int*)alloc((size_t)N * 4);
  int* col     = (int*)alloc((size_t)ET * 4);
  float* as1   = (float*)alloc((size_t)N * 4 * 4);
  float* ad1   = (float*)alloc((size_t)N * 4 * 4);
  float* mx1   = (float*)alloc((size_t)N * 4 * 4);
  float* inv1  = (float*)alloc((size_t)N * 4 * 4);
  float* as2   = (float*)alloc((size_t)N * 4);
  float* ad2   = (float*)alloc((size_t)N * 4);
  float* mx2   = (float*)alloc((size_t)N * 4);
  float* inv2  = (float*)alloc((size_t)N * 4);
  float* hl1   = (float*)alloc((size_t)N * D1 * 4);
  float* h1    = (float*)alloc((size_t)N * D1 * 4);
  float* h2    = hl1;   // reuse: hl1 dead after agg1
  float* out   = (float*)d_out;

  // CSR build (shared by both layers)
  hipLaunchKernelGGL(zero2_kernel, dim3((N + 255) / 256), dim3(256), 0, stream, deg, cur, N);
  hipLaunchKernelGGL(count_kernel, dim3((ET + 255) / 256), dim3(256), 0, stream, src, dst, deg, E, N);
  hipLaunchKernelGGL(scan_kernel, dim3(1), dim3(1024), 0, stream, deg, row_ptr, N);
  hipLaunchKernelGGL(scatter_kernel, dim3((ET + 255) / 256), dim3(256), 0, stream, src, dst, row_ptr, cur, col, E, N);

  // layer 1
  hipLaunchKernelGGL(gemm1_kernel, dim3((N + 63) / 64, 4), dim3(256), 0, stream, x, W1, hl1, N);
  hipLaunchKernelGGL(alpha1_kernel, dim3((N + 3) / 4), dim3(256), 0, stream, hl1, asrc1, adst1, as1, ad1, N);
  hipLaunchKernelGGL(stats1_kernel, dim3((N * 4 + 255) / 256), dim3(256), 0, stream, as1, ad1, row_ptr, col, mx1, inv1, N);
  hipLaunchKernelGGL(agg1_kernel, dim3((N + 3) / 4), dim3(256), 0, stream, hl1, as1, ad1, mx1, inv1, row_ptr, col, b1, h1, N);

  // layer 2
  hipLaunchKernelGGL(gemm2_kernel, dim3((N + 127) / 128), dim3(256), 0, stream, h1, W2, h2, N);
  hipLaunchKernelGGL(alpha2_kernel, dim3((N + 7) / 8), dim3(256), 0, stream, h2, asrc2, adst2, as2, ad2, N);
  hipLaunchKernelGGL(stats2_kernel, dim3((N + 255) / 256), dim3(256), 0, stream, as2, ad2, row_ptr, col, mx2, inv2, N);
  hipLaunchKernelGGL(agg2_kernel, dim3((N + 3) / 4), dim3(256), 0, stream, h2, as2, ad2, mx2, inv2, row_ptr, col, b2, out, N);
}

// Round 7
// 526.643 us; speedup vs baseline: 1.5969x; 1.1067x over previous
//
#include <hip/hip_runtime.h>
#include <hip/hip_fp16.h>
#include <math.h>

// Problem constants (from reference): F_in=256, H=4, HID=64 -> D1=256, OUT=32
#define FIN  256
#define D1   256
#define NHEAD 4
#define HIDC 64
#define DOUT 32
#define NSLOPE 0.2f

__device__ __forceinline__ float lrelu(float x) { return x >= 0.f ? x : NSLOPE * x; }

// ---------------- CSR construction ----------------
__global__ void zero2_kernel(int* __restrict__ a, int* __restrict__ b, int n) {
  int i = blockIdx.x * blockDim.x + threadIdx.x;
  if (i < n) { a[i] = 0; b[i] = 0; }
}

__global__ void count_kernel(const int* __restrict__ src, const int* __restrict__ dst,
                             int* __restrict__ deg, int E, int N) {
  int i = blockIdx.x * blockDim.x + threadIdx.x;
  if (i < E) {
    atomicAdd(&deg[dst[i]], 1);
  } else if (i < E + N) {
    atomicAdd(&deg[i - E], 1);   // self-loop
  }
}

__global__ __launch_bounds__(1024) void scan_kernel(const int* __restrict__ deg,
                                                    int* __restrict__ row_ptr, int N) {
  __shared__ int sh[1024];
  int t = threadIdx.x;
  int chunk = (N + 1023) / 1024;
  int b = t * chunk;
  int e = min(b + chunk, N);
  int s = 0;
  for (int i = b; i < e; ++i) s += deg[i];
  sh[t] = s;
  __syncthreads();
  // Hillis-Steele inclusive scan over 1024 partials
  for (int off = 1; off < 1024; off <<= 1) {
    int v = sh[t];
    int u = (t >= off) ? sh[t - off] : 0;
    __syncthreads();
    sh[t] = v + u;
    __syncthreads();
  }
  int run = sh[t] - s;   // exclusive prefix of this chunk
  for (int i = b; i < e; ++i) { run += deg[i]; row_ptr[i + 1] = run; }
  if (t == 0) row_ptr[0] = 0;
}

__global__ void scatter_kernel(const int* __restrict__ src, const int* __restrict__ dst,
                               const int* __restrict__ row_ptr, int* __restrict__ cur,
                               int* __restrict__ col, int E, int N) {
  int i = blockIdx.x * blockDim.x + threadIdx.x;
  int s, d;
  if (i < E) { s = src[i]; d = dst[i]; }
  else if (i < E + N) { s = i - E; d = i - E; }
  else return;
  int pos = row_ptr[d] + atomicAdd(&cur[d], 1);
  col[pos] = s;
}

// ---------------- GEMM1: [N,256] @ [256,256] -> fp16 [N,256] ----------------
__global__ __launch_bounds__(256) void gemm1_kernel(const float* __restrict__ A,
                                                    const float* __restrict__ B,
                                                    __half* __restrict__ C, int N) {
  __shared__ float xs[32][68];   // transposed A tile: xs[k][r]
  __shared__ float ws[32][68];   // B tile: ws[k][c]
  int t = threadIdx.x;
  int tx = t & 15, ty = t >> 4;
  int row0 = blockIdx.x * 64;
  int col0 = blockIdx.y * 64;
  float acc[4][4] = {};
  for (int k0 = 0; k0 < 256; k0 += 32) {
    // stage A tile (64 rows x 32 k), transposed
#pragma unroll
    for (int rep = 0; rep < 2; ++rep) {
      int r = (t >> 3) + rep * 32;
      int kk = (t & 7) * 4;
      int gr = row0 + r;
      float4 v = {0.f, 0.f, 0.f, 0.f};
      if (gr < N) v = *(const float4*)&A[(size_t)gr * FIN + k0 + kk];
      xs[kk + 0][r] = v.x; xs[kk + 1][r] = v.y; xs[kk + 2][r] = v.z; xs[kk + 3][r] = v.w;
    }
    // stage B tile (32 k x 64 cols)
#pragma unroll
    for (int rep = 0; rep < 2; ++rep) {
      int kk = (t >> 4) + rep * 16;
      int cc = (t & 15) * 4;
      float4 v = *(const float4*)&B[(size_t)(k0 + kk) * D1 + col0 + cc];
      *(float4*)&ws[kk][cc] = v;
    }
    __syncthreads();
#pragma unroll
    for (int k = 0; k < 32; ++k) {
      float4 av = *(const float4*)&xs[k][ty * 4];
      float4 bv = *(const float4*)&ws[k][tx * 4];
      float a_[4] = {av.x, av.y, av.z, av.w};
      float b_[4] = {bv.x, bv.y, bv.z, bv.w};
#pragma unroll
      for (int i = 0; i < 4; ++i)
#pragma unroll
        for (int j = 0; j < 4; ++j)
          acc[i][j] = fmaf(a_[i], b_[j], acc[i][j]);
    }
    __syncthreads();
  }
#pragma unroll
  for (int i = 0; i < 4; ++i) {
    int gr = row0 + ty * 4 + i;
    if (gr < N) {
      __half2 p0 = __floats2half2_rn(acc[i][0], acc[i][1]);
      __half2 p1 = __floats2half2_rn(acc[i][2], acc[i][3]);
      int2 pk;
      pk.x = *(int*)&p0;
      pk.y = *(int*)&p1;
      *(int2*)&C[(size_t)gr * D1 + col0 + tx * 4] = pk;
    }
  }
}

// ---------------- alpha1: per-node dot with att vectors (fp16 h) ----------------
__global__ __launch_bounds__(256) void alpha1_kernel(const __half* __restrict__ h,
                                                     const float* __restrict__ a_src,
                                                     const float* __restrict__ a_dst,
                                                     float* __restrict__ as,
                                                     float* __restrict__ ad, int N) {
  int wid = (blockIdx.x * blockDim.x + threadIdx.x) >> 6;
  if (wid >= N) return;
  int lane = threadIdx.x & 63;
  int2 r = *(const int2*)&h[(size_t)wid * D1 + lane * 4];
  float2 f01 = __half22float2(*(__half2*)&r.x);
  float2 f23 = __half22float2(*(__half2*)&r.y);
  float4 s4 = *(const float4*)&a_src[lane * 4];
  float4 d4 = *(const float4*)&a_dst[lane * 4];
  float ps = f01.x * s4.x + f01.y * s4.y + f23.x * s4.z + f23.y * s4.w;
  float pd = f01.x * d4.x + f01.y * d4.y + f23.x * d4.z + f23.y * d4.w;
#pragma unroll
  for (int off = 8; off >= 1; off >>= 1) {
    ps += __shfl_xor(ps, off);
    pd += __shfl_xor(pd, off);
  }
  int hh = lane >> 4;
  if ((lane & 15) == 0) { as[wid * 4 + hh] = ps; ad[wid * 4 + hh] = pd; }
}

// ---------------- stats1: per-(node,head) online softmax stats ----------------
__global__ __launch_bounds__(256) void stats1_kernel(const float* __restrict__ as1,
                                                     const float* __restrict__ ad1,
                                                     const int* __restrict__ row_ptr,
                                                     const int* __restrict__ col,
                                                     float* __restrict__ mx1,
                                                     float* __restrict__ inv1, int N) {
  int t = blockIdx.x * blockDim.x + threadIdx.x;
  if (t >= N * 4) return;
  int n = t >> 2, h = t & 3;
  int beg = row_ptr[n];
  int deg = row_ptr[n + 1] - beg;
  float adh = ad1[t];
  float m = -INFINITY, s = 0.f;
  int cn = col[beg];
  for (int j = 0; j < deg; ++j) {
    int c = cn;
    if (j + 1 < deg) cn = col[beg + j + 1];      // prefetch next col
    float e = lrelu(as1[(size_t)c * 4 + h] + adh);
    float nm = fmaxf(m, e);
    s = s * expf(m - nm) + expf(e - nm);         // expf(-inf)=0 first iter
    m = nm;
  }
  mx1[t] = m;
  inv1[t] = 1.f / (s + 1e-16f);
}

// ---------------- agg1: weighted aggregate, fp16 gather, 4-deep loads ----------------
__global__ __launch_bounds__(256) void agg1_kernel(const __half* __restrict__ hl,
                                                   const float* __restrict__ as1,
                                                   const float* __restrict__ ad1,
                                                   const float* __restrict__ mx1,
                                                   const float* __restrict__ inv1,
                                                   const int* __restrict__ row_ptr,
                                                   const int* __restrict__ col,
                                                   const float* __restrict__ b1,
                                                   float* __restrict__ h1, int N) {
  int wid = (blockIdx.x * blockDim.x + threadIdx.x) >> 6;
  if (wid >= N) return;
  int lane = threadIdx.x & 63;
  int hm = lane >> 4;
  int beg = row_ptr[wid];
  int deg = row_ptr[wid + 1] - beg;
  float adh = ad1[wid * 4 + hm];
  float mh  = mx1[wid * 4 + hm];
  float ih  = inv1[wid * 4 + hm];
  float4 acc = {0.f, 0.f, 0.f, 0.f};
  int j = 0;
  for (; j + 4 <= deg; j += 4) {
    int s0 = col[beg + j + 0];
    int s1 = col[beg + j + 1];
    int s2 = col[beg + j + 2];
    int s3 = col[beg + j + 3];
    float a0 = as1[(size_t)s0 * 4 + hm];
    float a1 = as1[(size_t)s1 * 4 + hm];
    float a2 = as1[(size_t)s2 * 4 + hm];
    float a3 = as1[(size_t)s3 * 4 + hm];
    int2 r0 = *(const int2*)&hl[(size_t)s0 * D1 + lane * 4];
    int2 r1 = *(const int2*)&hl[(size_t)s1 * D1 + lane * 4];
    int2 r2 = *(const int2*)&hl[(size_t)s2 * D1 + lane * 4];
    int2 r3 = *(const int2*)&hl[(size_t)s3 * D1 + lane * 4];
    float w0 = expf(lrelu(a0 + adh) - mh) * ih;
    float w1 = expf(lrelu(a1 + adh) - mh) * ih;
    float w2 = expf(lrelu(a2 + adh) - mh) * ih;
    float w3 = expf(lrelu(a3 + adh) - mh) * ih;
    float2 u, v;
    u = __half22float2(*(__half2*)&r0.x); v = __half22float2(*(__half2*)&r0.y);
    acc.x = fmaf(w0, u.x, acc.x); acc.y = fmaf(w0, u.y, acc.y);
    acc.z = fmaf(w0, v.x, acc.z); acc.w = fmaf(w0, v.y, acc.w);
    u = __half22float2(*(__half2*)&r1.x); v = __half22float2(*(__half2*)&r1.y);
    acc.x = fmaf(w1, u.x, acc.x); acc.y = fmaf(w1, u.y, acc.y);
    acc.z = fmaf(w1, v.x, acc.z); acc.w = fmaf(w1, v.y, acc.w);
    u = __half22float2(*(__half2*)&r2.x); v = __half22float2(*(__half2*)&r2.y);
    acc.x = fmaf(w2, u.x, acc.x); acc.y = fmaf(w2, u.y, acc.y);
    acc.z = fmaf(w2, v.x, acc.z); acc.w = fmaf(w2, v.y, acc.w);
    u = __half22float2(*(__half2*)&r3.x); v = __half22float2(*(__half2*)&r3.y);
    acc.x = fmaf(w3, u.x, acc.x); acc.y = fmaf(w3, u.y, acc.y);
    acc.z = fmaf(w3, v.x, acc.z); acc.w = fmaf(w3, v.y, acc.w);
  }
  for (; j < deg; ++j) {
    int s0 = col[beg + j];
    float a0 = as1[(size_t)s0 * 4 + hm];
    int2 r0 = *(const int2*)&hl[(size_t)s0 * D1 + lane * 4];
    float w0 = expf(lrelu(a0 + adh) - mh) * ih;
    float2 u = __half22float2(*(__half2*)&r0.x);
    float2 v = __half22float2(*(__half2*)&r0.y);
    acc.x = fmaf(w0, u.x, acc.x); acc.y = fmaf(w0, u.y, acc.y);
    acc.z = fmaf(w0, v.x, acc.z); acc.w = fmaf(w0, v.y, acc.w);
  }
  float4 bb = *(const float4*)&b1[lane * 4];
  float4 o;
  o.x = fmaxf(acc.x + bb.x, 0.f);
  o.y = fmaxf(acc.y + bb.y, 0.f);
  o.z = fmaxf(acc.z + bb.z, 0.f);
  o.w = fmaxf(acc.w + bb.w, 0.f);
  *(float4*)&h1[(size_t)wid * D1 + lane * 4] = o;
}

// ---------------- GEMM2: fp32 [N,256] @ [256,32] -> fp16 [N,32] ----------------
__global__ __launch_bounds__(256) void gemm2_kernel(const float* __restrict__ A,
                                                    const float* __restrict__ B,
                                                    __half* __restrict__ C, int N) {
  __shared__ float ws[256][33];   // full W2
  __shared__ float xs[32][132];   // transposed A chunk
  int t = threadIdx.x;
#pragma unroll
  for (int j = 0; j < 32; ++j) {
    int idx = j * 256 + t;
    ws[idx >> 5][idx & 31] = B[idx];
  }
  int row0 = blockIdx.x * 128;
  int tx = t & 31, ty = t >> 5;
  float acc[16] = {};
  for (int k0 = 0; k0 < 256; k0 += 32) {
    __syncthreads();
#pragma unroll
    for (int rep = 0; rep < 4; ++rep) {
      int r = (t >> 3) + rep * 32;
      int kk = (t & 7) * 4;
      int gr = row0 + r;
      float4 v = {0.f, 0.f, 0.f, 0.f};
      if (gr < N) v = *(const float4*)&A[(size_t)gr * D1 + k0 + kk];
      xs[kk + 0][r] = v.x; xs[kk + 1][r] = v.y; xs[kk + 2][r] = v.z; xs[kk + 3][r] = v.w;
    }
    __syncthreads();
#pragma unroll
    for (int k = 0; k < 32; ++k) {
      float w = ws[k0 + k][tx];
#pragma unroll
      for (int rq = 0; rq < 4; ++rq) {
        float4 a4 = *(const float4*)&xs[k][ty * 16 + rq * 4];
        acc[rq * 4 + 0] = fmaf(a4.x, w, acc[rq * 4 + 0]);
        acc[rq * 4 + 1] = fmaf(a4.y, w, acc[rq * 4 + 1]);
        acc[rq * 4 + 2] = fmaf(a4.z, w, acc[rq * 4 + 2]);
        acc[rq * 4 + 3] = fmaf(a4.w, w, acc[rq * 4 + 3]);
      }
    }
  }
#pragma unroll
  for (int j = 0; j < 16; ++j) {
    int gr = row0 + ty * 16 + j;
    if (gr < N) C[(size_t)gr * DOUT + tx] = __float2half(acc[j]);
  }
}

// ---------------- alpha2: one wave handles two nodes (fp16 h2) ----------------
__global__ __launch_bounds__(256) void alpha2_kernel(const __half* __restrict__ h2,
                                                     const float* __restrict__ a_src,
                                                     const float* __restrict__ a_dst,
                                                     float* __restrict__ as,
                                                     float* __restrict__ ad, int N) {
  int wid = (blockIdx.x * blockDim.x + threadIdx.x) >> 6;
  int lane = threadIdx.x & 63;
  int n = wid * 2 + (lane >> 5);
  int c = lane & 31;
  float v = (n < N) ? __half2float(h2[(size_t)n * DOUT + c]) : 0.f;
  float ps = v * a_src[c];
  float pd = v * a_dst[c];
#pragma unroll
  for (int off = 16; off >= 1; off >>= 1) {
    ps += __shfl_xor(ps, off);
    pd += __shfl_xor(pd, off);
  }
  if (c == 0 && n < N) { as[n] = ps; ad[n] = pd; }
}

// ---------------- stats2: per-node online softmax stats (H=1) ----------------
__global__ __launch_bounds__(256) void stats2_kernel(const float* __restrict__ as2,
                                                     const float* __restrict__ ad2,
                                                     const int* __restrict__ row_ptr,
                                                     const int* __restrict__ col,
                                                     float* __restrict__ mx2,
                                                     float* __restrict__ inv2, int N) {
  int n = blockIdx.x * blockDim.x + threadIdx.x;
  if (n >= N) return;
  int beg = row_ptr[n];
  int deg = row_ptr[n + 1] - beg;
  float ad = ad2[n];
  float m = -INFINITY, s = 0.f;
  int cn = col[beg];
  for (int j = 0; j < deg; ++j) {
    int c = cn;
    if (j + 1 < deg) cn = col[beg + j + 1];
    float e = lrelu(as2[c] + ad);
    float nm = fmaxf(m, e);
    s = s * expf(m - nm) + expf(e - nm);
    m = nm;
  }
  mx2[n] = m;
  inv2[n] = 1.f / (s + 1e-16f);
}

// ---------------- agg2: weighted aggregate (H=1, C=32), fp16 gather ----------------
__global__ __launch_bounds__(256) void agg2_kernel(const __half* __restrict__ h2,
                                                   const float* __restrict__ as2,
                                                   const float* __restrict__ ad2,
                                                   const float* __restrict__ mx2,
                                                   const float* __restrict__ inv2,
                                                   const int* __restrict__ row_ptr,
                                                   const int* __restrict__ col,
                                                   const float* __restrict__ b2,
                                                   float* __restrict__ out, int N) {
  int wid = (blockIdx.x * blockDim.x + threadIdx.x) >> 6;
  if (wid >= N) return;
  int lane = threadIdx.x & 63;
  int c = lane & 31;
  int beg = row_ptr[wid];
  int deg = row_ptr[wid + 1] - beg;
  float ad = ad2[wid];
  float mh = mx2[wid];
  float ih = inv2[wid];
  float acc = 0.f;
  int j = 0;
  for (; j + 4 <= deg; j += 4) {
    int s0 = col[beg + j + 0];
    int s1 = col[beg + j + 1];
    int s2 = col[beg + j + 2];
    int s3 = col[beg + j + 3];
    float a0 = as2[s0];
    float a1 = as2[s1];
    float a2 = as2[s2];
    float a3 = as2[s3];
    float v0 = __half2float(h2[(size_t)s0 * DOUT + c]);
    float v1 = __half2float(h2[(size_t)s1 * DOUT + c]);
    float v2 = __half2float(h2[(size_t)s2 * DOUT + c]);
    float v3 = __half2float(h2[(size_t)s3 * DOUT + c]);
    float w0 = expf(lrelu(a0 + ad) - mh) * ih;
    float w1 = expf(lrelu(a1 + ad) - mh) * ih;
    float w2 = expf(lrelu(a2 + ad) - mh) * ih;
    float w3 = expf(lrelu(a3 + ad) - mh) * ih;
    acc = fmaf(w0, v0, acc);
    acc = fmaf(w1, v1, acc);
    acc = fmaf(w2, v2, acc);
    acc = fmaf(w3, v3, acc);
  }
  for (; j < deg; ++j) {
    int s0 = col[beg + j];
    float a0 = as2[s0];
    float v0 = __half2float(h2[(size_t)s0 * DOUT + c]);
    float w0 = expf(lrelu(a0 + ad) - mh) * ih;
    acc = fmaf(w0, v0, acc);
  }
  if (lane < 32) out[(size_t)wid * DOUT + c] = acc + b2[c];
}

// ---------------- launch ----------------
extern "C" void kernel_launch(void* const* d_in, const int* in_sizes, int n_in,
                              void* d_out, int out_size, void* d_ws, size_t ws_size,
                              hipStream_t stream) {
  const float* x     = (const float*)d_in[0];
  const int*   ei    = (const int*)d_in[1];
  const float* W1    = (const float*)d_in[2];
  const float* asrc1 = (const float*)d_in[3];
  const float* adst1 = (const float*)d_in[4];
  const float* b1    = (const float*)d_in[5];
  const float* W2    = (const float*)d_in[6];
  const float* asrc2 = (const float*)d_in[7];
  const float* adst2 = (const float*)d_in[8];
  const float* b2    = (const float*)d_in[9];

  const int N = in_sizes[0] / FIN;
  const int E = in_sizes[1] / 2;
  const int ET = E + N;
  const int* src = ei;
  const int* dst = ei + E;

  char* base = (char*)d_ws;
  size_t off = 0;
  auto alloc = [&](size_t bytes) -> void* {
    void* p = base + off;
    off = (off + bytes + 255) & ~(size_t)255;
    return p;
  };
  int* row_ptr = (int*)alloc((size_t)(N + 1) * 4);
  int* deg     = (int*)alloc((size_t)N * 4);
  int* cur     = (int*)alloc((size_t)N * 4);
  int* col     = (int*)alloc((size_t)ET * 4);
  float* as1   = (float*)alloc((size_t)N * 4 * 4);
  float* ad1   = (float*)alloc((size_t)N * 4 * 4);
  float* mx1   = (float*)alloc((size_t)N * 4 * 4);
  float* inv1  = (float*)alloc((size_t)N * 4 * 4);
  float* as2   = (float*)alloc((size_t)N * 4);
  float* ad2   = (float*)alloc((size_t)N * 4);
  float* mx2   = (float*)alloc((size_t)N * 4);
  float* inv2  = (float*)alloc((size_t)N * 4);
  __half* hl1  = (__half*)alloc((size_t)N * D1 * 2);   // fp16 gather source L1
  float* h1    = (float*)alloc((size_t)N * D1 * 4);    // fp32, streamed by gemm2
  __half* h2   = hl1;   // reuse: hl1 dead after agg1; fp16 gather source L2
  float* out   = (float*)d_out;

  // CSR build (shared by both layers)
  hipLaunchKernelGGL(zero2_kernel, dim3((N + 255) / 256), dim3(256), 0, stream, deg, cur, N);
  hipLaunchKernelGGL(count_kernel, dim3((ET + 255) / 256), dim3(256), 0, stream, src, dst, deg, E, N);
  hipLaunchKernelGGL(scan_kernel, dim3(1), dim3(1024), 0, stream, deg, row_ptr, N);
  hipLaunchKernelGGL(scatter_kernel, dim3((ET + 255) / 256), dim3(256), 0, stream, src, dst, row_ptr, cur, col, E, N);

  // layer 1
  hipLaunchKernelGGL(gemm1_kernel, dim3((N + 63) / 64, 4), dim3(256), 0, stream, x, W1, hl1, N);
  hipLaunchKernelGGL(alpha1_kernel, dim3((N + 3) / 4), dim3(256), 0, stream, hl1, asrc1, adst1, as1, ad1, N);
  hipLaunchKernelGGL(stats1_kernel, dim3((N * 4 + 255) / 256), dim3(256), 0, stream, as1, ad1, row_ptr, col, mx1, inv1, N);
  hipLaunchKernelGGL(agg1_kernel, dim3((N + 3) / 4), dim3(256), 0, stream, hl1, as1, ad1, mx1, inv1, row_ptr, col, b1, h1, N);

  // layer 2
  hipLaunchKernelGGL(gemm2_kernel, dim3((N + 127) / 128), dim3(256), 0, stream, h1, W2, h2, N);
  hipLaunchKernelGGL(alpha2_kernel, dim3((N + 7) / 8), dim3(256), 0, stream, h2, asrc2, adst2, as2, ad2, N);
  hipLaunchKernelGGL(stats2_kernel, dim3((N + 255) / 256), dim3(256), 0, stream, as2, ad2, row_ptr, col, mx2, inv2, N);
  hipLaunchKernelGGL(agg2_kernel, dim3((N + 3) / 4), dim3(256), 0, stream, h2, as2, ad2, mx2, inv2, row_ptr, col, b2, out, N);
}

// Round 8
// 522.974 us; speedup vs baseline: 1.6081x; 1.0070x over previous
//
#include <hip/hip_runtime.h>
#include <hip/hip_fp16.h>
#include <math.h>

// Problem constants (from reference): F_in=256, H=4, HID=64 -> D1=256, OUT=32
#define FIN  256
#define D1   256
#define NHEAD 4
#define HIDC 64
#define DOUT 32
#define NSLOPE 0.2f

__device__ __forceinline__ float lrelu(float x) { return x >= 0.f ? x : NSLOPE * x; }

// ---------------- CSR construction ----------------
__global__ void zero2_kernel(int* __restrict__ a, int* __restrict__ b, int n) {
  int i = blockIdx.x * blockDim.x + threadIdx.x;
  if (i < n) { a[i] = 0; b[i] = 0; }
}

__global__ void count_kernel(const int* __restrict__ src, const int* __restrict__ dst,
                             int* __restrict__ deg, int E, int N) {
  int i = blockIdx.x * blockDim.x + threadIdx.x;
  if (i < E) {
    atomicAdd(&deg[dst[i]], 1);
  } else if (i < E + N) {
    atomicAdd(&deg[i - E], 1);   // self-loop
  }
}

__global__ __launch_bounds__(1024) void scan_kernel(const int* __restrict__ deg,
                                                    int* __restrict__ row_ptr, int N) {
  __shared__ int sh[1024];
  int t = threadIdx.x;
  int chunk = (N + 1023) / 1024;
  int b = t * chunk;
  int e = min(b + chunk, N);
  int s = 0;
  for (int i = b; i < e; ++i) s += deg[i];
  sh[t] = s;
  __syncthreads();
  // Hillis-Steele inclusive scan over 1024 partials
  for (int off = 1; off < 1024; off <<= 1) {
    int v = sh[t];
    int u = (t >= off) ? sh[t - off] : 0;
    __syncthreads();
    sh[t] = v + u;
    __syncthreads();
  }
  int run = sh[t] - s;   // exclusive prefix of this chunk
  for (int i = b; i < e; ++i) { run += deg[i]; row_ptr[i + 1] = run; }
  if (t == 0) row_ptr[0] = 0;
}

__global__ void scatter_kernel(const int* __restrict__ src, const int* __restrict__ dst,
                               const int* __restrict__ row_ptr, int* __restrict__ cur,
                               int* __restrict__ col, int E, int N) {
  int i = blockIdx.x * blockDim.x + threadIdx.x;
  int s, d;
  if (i < E) { s = src[i]; d = dst[i]; }
  else if (i < E + N) { s = i - E; d = i - E; }
  else return;
  int pos = row_ptr[d] + atomicAdd(&cur[d], 1);
  col[pos] = s;
}

// ---------------- GEMM1: [N,256] @ [256,256] -> fp16 [N,256] ----------------
// 128x128 tile, 8x8 per thread (split 4+4 rows/cols), fp32 math, fp16 out.
__global__ __launch_bounds__(256) void gemm1_kernel(const float* __restrict__ A,
                                                    const float* __restrict__ B,
                                                    __half* __restrict__ C, int N) {
  __shared__ float xs[32][132];   // [k][row], transposed A tile
  __shared__ float ws[32][132];   // [k][col], B tile
  int t = threadIdx.x;
  int row0 = blockIdx.x * 128;
  int col0 = blockIdx.y * 128;
  int tr = t >> 4;    // 0..15 (row group)
  int tc = t & 15;    // 0..15 (col group)
  float acc[2][2][4][4] = {};
  for (int k0 = 0; k0 < 256; k0 += 32) {
    // stage A: 128 rows x 32 k, transposed. 8 lanes cover one row's 128B k-chunk.
    {
      int kk = (t & 7) * 4;
      int rb = t >> 3;                       // 0..31
#pragma unroll
      for (int rep = 0; rep < 4; ++rep) {
        int r = rb + rep * 32;
        int gr = row0 + r;
        float4 v = {0.f, 0.f, 0.f, 0.f};
        if (gr < N) v = *(const float4*)&A[(size_t)gr * FIN + k0 + kk];
        xs[kk + 0][r] = v.x; xs[kk + 1][r] = v.y; xs[kk + 2][r] = v.z; xs[kk + 3][r] = v.w;
      }
    }
    // stage B: 32 k x 128 cols, natural layout
    {
      int cc = (t & 31) * 4;
      int kb = t >> 5;                       // 0..7
#pragma unroll
      for (int rep = 0; rep < 4; ++rep) {
        int kk = kb + rep * 8;
        float4 v = *(const float4*)&B[(size_t)(k0 + kk) * D1 + col0 + cc];
        *(float4*)&ws[kk][cc] = v;
      }
    }
    __syncthreads();
#pragma unroll
    for (int k = 0; k < 32; ++k) {
      float4 a0 = *(const float4*)&xs[k][tr * 4];
      float4 a1 = *(const float4*)&xs[k][64 + tr * 4];
      float4 b0 = *(const float4*)&ws[k][tc * 4];
      float4 b1 = *(const float4*)&ws[k][64 + tc * 4];
      float av[2][4] = {{a0.x, a0.y, a0.z, a0.w}, {a1.x, a1.y, a1.z, a1.w}};
      float bv[2][4] = {{b0.x, b0.y, b0.z, b0.w}, {b1.x, b1.y, b1.z, b1.w}};
#pragma unroll
      for (int qi = 0; qi < 2; ++qi)
#pragma unroll
        for (int i = 0; i < 4; ++i)
#pragma unroll
          for (int qj = 0; qj < 2; ++qj)
#pragma unroll
            for (int j = 0; j < 4; ++j)
              acc[qi][qj][i][j] = fmaf(av[qi][i], bv[qj][j], acc[qi][qj][i][j]);
    }
    __syncthreads();
  }
  // epilogue: pack to fp16, 8B writes
#pragma unroll
  for (int qi = 0; qi < 2; ++qi)
#pragma unroll
    for (int i = 0; i < 4; ++i) {
      int gr = row0 + qi * 64 + tr * 4 + i;
      if (gr < N) {
#pragma unroll
        for (int qj = 0; qj < 2; ++qj) {
          __half2 p0 = __floats2half2_rn(acc[qi][qj][i][0], acc[qi][qj][i][1]);
          __half2 p1 = __floats2half2_rn(acc[qi][qj][i][2], acc[qi][qj][i][3]);
          int2 pk;
          pk.x = *(int*)&p0;
          pk.y = *(int*)&p1;
          *(int2*)&C[(size_t)gr * D1 + col0 + qj * 64 + tc * 4] = pk;
        }
      }
    }
}

// ---------------- alpha1: per-node dot with att vectors (fp16 h) ----------------
__global__ __launch_bounds__(256) void alpha1_kernel(const __half* __restrict__ h,
                                                     const float* __restrict__ a_src,
                                                     const float* __restrict__ a_dst,
                                                     float* __restrict__ as,
                                                     float* __restrict__ ad, int N) {
  int wid = (blockIdx.x * blockDim.x + threadIdx.x) >> 6;
  if (wid >= N) return;
  int lane = threadIdx.x & 63;
  int2 r = *(const int2*)&h[(size_t)wid * D1 + lane * 4];
  float2 f01 = __half22float2(*(__half2*)&r.x);
  float2 f23 = __half22float2(*(__half2*)&r.y);
  float4 s4 = *(const float4*)&a_src[lane * 4];
  float4 d4 = *(const float4*)&a_dst[lane * 4];
  float ps = f01.x * s4.x + f01.y * s4.y + f23.x * s4.z + f23.y * s4.w;
  float pd = f01.x * d4.x + f01.y * d4.y + f23.x * d4.z + f23.y * d4.w;
#pragma unroll
  for (int off = 8; off >= 1; off >>= 1) {
    ps += __shfl_xor(ps, off);
    pd += __shfl_xor(pd, off);
  }
  int hh = lane >> 4;
  if ((lane & 15) == 0) { as[wid * 4 + hh] = ps; ad[wid * 4 + hh] = pd; }
}

// ---------------- stats1: per-(node,head) online softmax stats ----------------
__global__ __launch_bounds__(256) void stats1_kernel(const float* __restrict__ as1,
                                                     const float* __restrict__ ad1,
                                                     const int* __restrict__ row_ptr,
                                                     const int* __restrict__ col,
                                                     float* __restrict__ mx1,
                                                     float* __restrict__ inv1, int N) {
  int t = blockIdx.x * blockDim.x + threadIdx.x;
  if (t >= N * 4) return;
  int n = t >> 2, h = t & 3;
  int beg = row_ptr[n];
  int deg = row_ptr[n + 1] - beg;
  float adh = ad1[t];
  float m = -INFINITY, s = 0.f;
  int cn = col[beg];
  for (int j = 0; j < deg; ++j) {
    int c = cn;
    if (j + 1 < deg) cn = col[beg + j + 1];      // prefetch next col
    float e = lrelu(as1[(size_t)c * 4 + h] + adh);
    float nm = fmaxf(m, e);
    s = s * expf(m - nm) + expf(e - nm);         // expf(-inf)=0 first iter
    m = nm;
  }
  mx1[t] = m;
  inv1[t] = 1.f / (s + 1e-16f);
}

// ---------------- agg1: weighted aggregate, fp16 gather, 4-deep loads ----------------
__global__ __launch_bounds__(256) void agg1_kernel(const __half* __restrict__ hl,
                                                   const float* __restrict__ as1,
                                                   const float* __restrict__ ad1,
                                                   const float* __restrict__ mx1,
                                                   const float* __restrict__ inv1,
                                                   const int* __restrict__ row_ptr,
                                                   const int* __restrict__ col,
                                                   const float* __restrict__ b1,
                                                   float* __restrict__ h1, int N) {
  int wid = (blockIdx.x * blockDim.x + threadIdx.x) >> 6;
  if (wid >= N) return;
  int lane = threadIdx.x & 63;
  int hm = lane >> 4;
  int beg = row_ptr[wid];
  int deg = row_ptr[wid + 1] - beg;
  float adh = ad1[wid * 4 + hm];
  float mh  = mx1[wid * 4 + hm];
  float ih  = inv1[wid * 4 + hm];
  float4 acc = {0.f, 0.f, 0.f, 0.f};
  int j = 0;
  for (; j + 4 <= deg; j += 4) {
    int s0 = col[beg + j + 0];
    int s1 = col[beg + j + 1];
    int s2 = col[beg + j + 2];
    int s3 = col[beg + j + 3];
    float a0 = as1[(size_t)s0 * 4 + hm];
    float a1 = as1[(size_t)s1 * 4 + hm];
    float a2 = as1[(size_t)s2 * 4 + hm];
    float a3 = as1[(size_t)s3 * 4 + hm];
    int2 r0 = *(const int2*)&hl[(size_t)s0 * D1 + lane * 4];
    int2 r1 = *(const int2*)&hl[(size_t)s1 * D1 + lane * 4];
    int2 r2 = *(const int2*)&hl[(size_t)s2 * D1 + lane * 4];
    int2 r3 = *(const int2*)&hl[(size_t)s3 * D1 + lane * 4];
    float w0 = expf(lrelu(a0 + adh) - mh) * ih;
    float w1 = expf(lrelu(a1 + adh) - mh) * ih;
    float w2 = expf(lrelu(a2 + adh) - mh) * ih;
    float w3 = expf(lrelu(a3 + adh) - mh) * ih;
    float2 u, v;
    u = __half22float2(*(__half2*)&r0.x); v = __half22float2(*(__half2*)&r0.y);
    acc.x = fmaf(w0, u.x, acc.x); acc.y = fmaf(w0, u.y, acc.y);
    acc.z = fmaf(w0, v.x, acc.z); acc.w = fmaf(w0, v.y, acc.w);
    u = __half22float2(*(__half2*)&r1.x); v = __half22float2(*(__half2*)&r1.y);
    acc.x = fmaf(w1, u.x, acc.x); acc.y = fmaf(w1, u.y, acc.y);
    acc.z = fmaf(w1, v.x, acc.z); acc.w = fmaf(w1, v.y, acc.w);
    u = __half22float2(*(__half2*)&r2.x); v = __half22float2(*(__half2*)&r2.y);
    acc.x = fmaf(w2, u.x, acc.x); acc.y = fmaf(w2, u.y, acc.y);
    acc.z = fmaf(w2, v.x, acc.z); acc.w = fmaf(w2, v.y, acc.w);
    u = __half22float2(*(__half2*)&r3.x); v = __half22float2(*(__half2*)&r3.y);
    acc.x = fmaf(w3, u.x, acc.x); acc.y = fmaf(w3, u.y, acc.y);
    acc.z = fmaf(w3, v.x, acc.z); acc.w = fmaf(w3, v.y, acc.w);
  }
  for (; j < deg; ++j) {
    int s0 = col[beg + j];
    float a0 = as1[(size_t)s0 * 4 + hm];
    int2 r0 = *(const int2*)&hl[(size_t)s0 * D1 + lane * 4];
    float w0 = expf(lrelu(a0 + adh) - mh) * ih;
    float2 u = __half22float2(*(__half2*)&r0.x);
    float2 v = __half22float2(*(__half2*)&r0.y);
    acc.x = fmaf(w0, u.x, acc.x); acc.y = fmaf(w0, u.y, acc.y);
    acc.z = fmaf(w0, v.x, acc.z); acc.w = fmaf(w0, v.y, acc.w);
  }
  float4 bb = *(const float4*)&b1[lane * 4];
  float4 o;
  o.x = fmaxf(acc.x + bb.x, 0.f);
  o.y = fmaxf(acc.y + bb.y, 0.f);
  o.z = fmaxf(acc.z + bb.z, 0.f);
  o.w = fmaxf(acc.w + bb.w, 0.f);
  *(float4*)&h1[(size_t)wid * D1 + lane * 4] = o;
}

// ---------------- GEMM2: fp32 [N,256] @ [256,32] -> fp16 [N,32] ----------------
__global__ __launch_bounds__(256) void gemm2_kernel(const float* __restrict__ A,
                                                    const float* __restrict__ B,
                                                    __half* __restrict__ C, int N) {
  __shared__ float ws[256][33];   // full W2
  __shared__ float xs[32][132];   // transposed A chunk
  int t = threadIdx.x;
#pragma unroll
  for (int j = 0; j < 32; ++j) {
    int idx = j * 256 + t;
    ws[idx >> 5][idx & 31] = B[idx];
  }
  int row0 = blockIdx.x * 128;
  int tx = t & 31, ty = t >> 5;
  float acc[16] = {};
  for (int k0 = 0; k0 < 256; k0 += 32) {
    __syncthreads();
#pragma unroll
    for (int rep = 0; rep < 4; ++rep) {
      int r = (t >> 3) + rep * 32;
      int kk = (t & 7) * 4;
      int gr = row0 + r;
      float4 v = {0.f, 0.f, 0.f, 0.f};
      if (gr < N) v = *(const float4*)&A[(size_t)gr * D1 + k0 + kk];
      xs[kk + 0][r] = v.x; xs[kk + 1][r] = v.y; xs[kk + 2][r] = v.z; xs[kk + 3][r] = v.w;
    }
    __syncthreads();
#pragma unroll
    for (int k = 0; k < 32; ++k) {
      float w = ws[k0 + k][tx];
#pragma unroll
      for (int rq = 0; rq < 4; ++rq) {
        float4 a4 = *(const float4*)&xs[k][ty * 16 + rq * 4];
        acc[rq * 4 + 0] = fmaf(a4.x, w, acc[rq * 4 + 0]);
        acc[rq * 4 + 1] = fmaf(a4.y, w, acc[rq * 4 + 1]);
        acc[rq * 4 + 2] = fmaf(a4.z, w, acc[rq * 4 + 2]);
        acc[rq * 4 + 3] = fmaf(a4.w, w, acc[rq * 4 + 3]);
      }
    }
  }
#pragma unroll
  for (int j = 0; j < 16; ++j) {
    int gr = row0 + ty * 16 + j;
    if (gr < N) C[(size_t)gr * DOUT + tx] = __float2half(acc[j]);
  }
}

// ---------------- alpha2: one wave handles two nodes (fp16 h2) ----------------
__global__ __launch_bounds__(256) void alpha2_kernel(const __half* __restrict__ h2,
                                                     const float* __restrict__ a_src,
                                                     const float* __restrict__ a_dst,
                                                     float* __restrict__ as,
                                                     float* __restrict__ ad, int N) {
  int wid = (blockIdx.x * blockDim.x + threadIdx.x) >> 6;
  int lane = threadIdx.x & 63;
  int n = wid * 2 + (lane >> 5);
  int c = lane & 31;
  float v = (n < N) ? __half2float(h2[(size_t)n * DOUT + c]) : 0.f;
  float ps = v * a_src[c];
  float pd = v * a_dst[c];
#pragma unroll
  for (int off = 16; off >= 1; off >>= 1) {
    ps += __shfl_xor(ps, off);
    pd += __shfl_xor(pd, off);
  }
  if (c == 0 && n < N) { as[n] = ps; ad[n] = pd; }
}

// ---------------- stats2: per-node online softmax stats (H=1) ----------------
__global__ __launch_bounds__(256) void stats2_kernel(const float* __restrict__ as2,
                                                     const float* __restrict__ ad2,
                                                     const int* __restrict__ row_ptr,
                                                     const int* __restrict__ col,
                                                     float* __restrict__ mx2,
                                                     float* __restrict__ inv2, int N) {
  int n = blockIdx.x * blockDim.x + threadIdx.x;
  if (n >= N) return;
  int beg = row_ptr[n];
  int deg = row_ptr[n + 1] - beg;
  float ad = ad2[n];
  float m = -INFINITY, s = 0.f;
  int cn = col[beg];
  for (int j = 0; j < deg; ++j) {
    int c = cn;
    if (j + 1 < deg) cn = col[beg + j + 1];
    float e = lrelu(as2[c] + ad);
    float nm = fmaxf(m, e);
    s = s * expf(m - nm) + expf(e - nm);
    m = nm;
  }
  mx2[n] = m;
  inv2[n] = 1.f / (s + 1e-16f);
}

// ---------------- agg2: weighted aggregate (H=1, C=32), fp16 gather ----------------
__global__ __launch_bounds__(256) void agg2_kernel(const __half* __restrict__ h2,
                                                   const float* __restrict__ as2,
                                                   const float* __restrict__ ad2,
                                                   const float* __restrict__ mx2,
                                                   const float* __restrict__ inv2,
                                                   const int* __restrict__ row_ptr,
                                                   const int* __restrict__ col,
                                                   const float* __restrict__ b2,
                                                   float* __restrict__ out, int N) {
  int wid = (blockIdx.x * blockDim.x + threadIdx.x) >> 6;
  if (wid >= N) return;
  int lane = threadIdx.x & 63;
  int c = lane & 31;
  int beg = row_ptr[wid];
  int deg = row_ptr[wid + 1] - beg;
  float ad = ad2[wid];
  float mh = mx2[wid];
  float ih = inv2[wid];
  float acc = 0.f;
  int j = 0;
  for (; j + 4 <= deg; j += 4) {
    int s0 = col[beg + j + 0];
    int s1 = col[beg + j + 1];
    int s2 = col[beg + j + 2];
    int s3 = col[beg + j + 3];
    float a0 = as2[s0];
    float a1 = as2[s1];
    float a2 = as2[s2];
    float a3 = as2[s3];
    float v0 = __half2float(h2[(size_t)s0 * DOUT + c]);
    float v1 = __half2float(h2[(size_t)s1 * DOUT + c]);
    float v2 = __half2float(h2[(size_t)s2 * DOUT + c]);
    float v3 = __half2float(h2[(size_t)s3 * DOUT + c]);
    float w0 = expf(lrelu(a0 + ad) - mh) * ih;
    float w1 = expf(lrelu(a1 + ad) - mh) * ih;
    float w2 = expf(lrelu(a2 + ad) - mh) * ih;
    float w3 = expf(lrelu(a3 + ad) - mh) * ih;
    acc = fmaf(w0, v0, acc);
    acc = fmaf(w1, v1, acc);
    acc = fmaf(w2, v2, acc);
    acc = fmaf(w3, v3, acc);
  }
  for (; j < deg; ++j) {
    int s0 = col[beg + j];
    float a0 = as2[s0];
    float v0 = __half2float(h2[(size_t)s0 * DOUT + c]);
    float w0 = expf(lrelu(a0 + ad) - mh) * ih;
    acc = fmaf(w0, v0, acc);
  }
  if (lane < 32) out[(size_t)wid * DOUT + c] = acc + b2[c];
}

// ---------------- launch ----------------
extern "C" void kernel_launch(void* const* d_in, const int* in_sizes, int n_in,
                              void* d_out, int out_size, void* d_ws, size_t ws_size,
                              hipStream_t stream) {
  const float* x     = (const float*)d_in[0];
  const int*   ei    = (const int*)d_in[1];
  const float* W1    = (const float*)d_in[2];
  const float* asrc1 = (const float*)d_in[3];
  const float* adst1 = (const float*)d_in[4];
  const float* b1    = (const float*)d_in[5];
  const float* W2    = (const float*)d_in[6];
  const float* asrc2 = (const float*)d_in[7];
  const float* adst2 = (const float*)d_in[8];
  const float* b2    = (const float*)d_in[9];

  const int N = in_sizes[0] / FIN;
  const int E = in_sizes[1] / 2;
  const int ET = E + N;
  const int* src = ei;
  const int* dst = ei + E;

  char* base = (char*)d_ws;
  size_t off = 0;
  auto alloc = [&](size_t bytes) -> void* {
    void* p = base + off;
    off = (off + bytes + 255) & ~(size_t)255;
    return p;
  };
  int* row_ptr = (int*)alloc((size_t)(N + 1) * 4);
  int* deg     = (int*)alloc((size_t)N * 4);
  int* cur     = (int*)alloc((size_t)N * 4);
  int* col     = (int*)alloc((size_t)ET * 4);
  float* as1   = (float*)alloc((size_t)N * 4 * 4);
  float* ad1   = (float*)alloc((size_t)N * 4 * 4);
  float* mx1   = (float*)alloc((size_t)N * 4 * 4);
  float* inv1  = (float*)alloc((size_t)N * 4 * 4);
  float* as2   = (float*)alloc((size_t)N * 4);
  float* ad2   = (float*)alloc((size_t)N * 4);
  float* mx2   = (float*)alloc((size_t)N * 4);
  float* inv2  = (float*)alloc((size_t)N * 4);
  __half* hl1  = (__half*)alloc((size_t)N * D1 * 2);   // fp16 gather source L1
  float* h1    = (float*)alloc((size_t)N * D1 * 4);    // fp32, streamed by gemm2
  __half* h2   = hl1;   // reuse: hl1 dead after agg1; fp16 gather source L2
  float* out   = (float*)d_out;

  // CSR build (shared by both layers)
  hipLaunchKernelGGL(zero2_kernel, dim3((N + 255) / 256), dim3(256), 0, stream, deg, cur, N);
  hipLaunchKernelGGL(count_kernel, dim3((ET + 255) / 256), dim3(256), 0, stream, src, dst, deg, E, N);
  hipLaunchKernelGGL(scan_kernel, dim3(1), dim3(1024), 0, stream, deg, row_ptr, N);
  hipLaunchKernelGGL(scatter_kernel, dim3((ET + 255) / 256), dim3(256), 0, stream, src, dst, row_ptr, cur, col, E, N);

  // layer 1
  hipLaunchKernelGGL(gemm1_kernel, dim3((N + 127) / 128, 2), dim3(256), 0, stream, x, W1, hl1, N);
  hipLaunchKernelGGL(alpha1_kernel, dim3((N + 3) / 4), dim3(256), 0, stream, hl1, asrc1, adst1, as1, ad1, N);
  hipLaunchKernelGGL(stats1_kernel, dim3((N * 4 + 255) / 256), dim3(256), 0, stream, as1, ad1, row_ptr, col, mx1, inv1, N);
  hipLaunchKernelGGL(agg1_kernel, dim3((N + 3) / 4), dim3(256), 0, stream, hl1, as1, ad1, mx1, inv1, row_ptr, col, b1, h1, N);

  // layer 2
  hipLaunchKernelGGL(gemm2_kernel, dim3((N + 127) / 128), dim3(256), 0, stream, h1, W2, h2, N);
  hipLaunchKernelGGL(alpha2_kernel, dim3((N + 7) / 8), dim3(256), 0, stream, h2, asrc2, adst2, as2, ad2, N);
  hipLaunchKernelGGL(stats2_kernel, dim3((N + 255) / 256), dim3(256), 0, stream, as2, ad2, row_ptr, col, mx2, inv2, N);
  hipLaunchKernelGGL(agg2_kernel, dim3((N + 3) / 4), dim3(256), 0, stream, h2, as2, ad2, mx2, inv2, row_ptr, col, b2, out, N);
}

// Round 12
// 492.434 us; speedup vs baseline: 1.7079x; 1.0620x over previous
//
#include <hip/hip_runtime.h>
#include <hip/hip_fp16.h>
#include <math.h>

// Problem constants (from reference): F_in=256, H=4, HID=64 -> D1=256, OUT=32
#define FIN  256
#define D1   256
#define NHEAD 4
#define HIDC 64
#define DOUT 32
#define NSLOPE 0.2f

typedef __attribute__((ext_vector_type(8))) short short8v;   // 8 bf16 = 4 VGPR
typedef __attribute__((ext_vector_type(4))) float f32x4;     // MFMA acc

__device__ __forceinline__ float lrelu(float x) { return x >= 0.f ? x : NSLOPE * x; }

// round-to-nearest-even fp32 -> bf16 split: x ~= hi + lo (both bf16)
__device__ __forceinline__ void bf16split(float x, unsigned short& h, unsigned short& l) {
  unsigned u = __float_as_uint(x);
  unsigned uh = (u + 0x7fffu + ((u >> 16) & 1u)) & 0xffff0000u;
  h = (unsigned short)(uh >> 16);
  float r = x - __uint_as_float(uh);
  unsigned ur = __float_as_uint(r);
  l = (unsigned short)((ur + 0x7fffu + ((ur >> 16) & 1u)) >> 16);
}

// ---------------- CSR construction ----------------
__global__ void zero2_kernel(int* __restrict__ a, int* __restrict__ b, int n) {
  int i = blockIdx.x * blockDim.x + threadIdx.x;
  if (i < n) { a[i] = 0; b[i] = 0; }
}

__global__ void count_kernel(const int* __restrict__ src, const int* __restrict__ dst,
                             int* __restrict__ deg, int E, int N) {
  int i = blockIdx.x * blockDim.x + threadIdx.x;
  if (i < E) {
    atomicAdd(&deg[dst[i]], 1);
  } else if (i < E + N) {
    atomicAdd(&deg[i - E], 1);   // self-loop
  }
}

__global__ __launch_bounds__(1024) void scan_kernel(const int* __restrict__ deg,
                                                    int* __restrict__ row_ptr, int N) {
  __shared__ int sh[1024];
  int t = threadIdx.x;
  int chunk = (N + 1023) / 1024;
  int b = t * chunk;
  int e = min(b + chunk, N);
  int s = 0;
  for (int i = b; i < e; ++i) s += deg[i];
  sh[t] = s;
  __syncthreads();
  for (int off = 1; off < 1024; off <<= 1) {
    int v = sh[t];
    int u = (t >= off) ? sh[t - off] : 0;
    __syncthreads();
    sh[t] = v + u;
    __syncthreads();
  }
  int run = sh[t] - s;
  for (int i = b; i < e; ++i) { run += deg[i]; row_ptr[i + 1] = run; }
  if (t == 0) row_ptr[0] = 0;
}

__global__ void scatter_kernel(const int* __restrict__ src, const int* __restrict__ dst,
                               const int* __restrict__ row_ptr, int* __restrict__ cur,
                               int* __restrict__ col, int E, int N) {
  int i = blockIdx.x * blockDim.x + threadIdx.x;
  int s, d;
  if (i < E) { s = src[i]; d = dst[i]; }
  else if (i < E + N) { s = i - E; d = i - E; }
  else return;
  int pos = row_ptr[d] + atomicAdd(&cur[d], 1);
  col[pos] = s;
}

// ---------------- W1 split+transpose: W1[k][c] -> Wt_hi/lo[c][k] (bf16) ----------------
__global__ __launch_bounds__(256) void splitW1_kernel(const float* __restrict__ W1,
                                                      unsigned short* __restrict__ Wt_hi,
                                                      unsigned short* __restrict__ Wt_lo) {
  int t = blockIdx.x * 256 + threadIdx.x;   // 65536 threads
  int c = t >> 8, k = t & 255;              // write coalesced over k
  float x = W1[(size_t)k * D1 + c];
  unsigned short h, l;
  bf16split(x, h, l);
  Wt_hi[(size_t)c * FIN + k] = h;
  Wt_lo[(size_t)c * FIN + k] = l;
}

// ---------------- GEMM1 (MFMA split-bf16): [N,256] @ [256,256] -> fp16 ----------------
// Block: 64 rows x 256 cols, BK=32, 4 waves (wave w owns cols [w*64, w*64+64)).
// x split to bf16 hi/lo in-kernel; W pre-split/transposed in global.
// Frag layouts (gfx950 mfma_f32_16x16x32_bf16):
//   A: lane holds A[lane&15][(lane>>4)*8 + j]   (8 k per lane)
//   B: lane holds B[(lane>>4)*8 + j][lane&15]
//   D: col=lane&15, row=(lane>>4)*4+reg  [m89-verified]
// (a shared k-permutation between A and B fragments cancels algebraically)
__global__ __launch_bounds__(256) void gemm1_kernel(const float* __restrict__ A,
                                                    const unsigned short* __restrict__ Bt_hi,
                                                    const unsigned short* __restrict__ Bt_lo,
                                                    __half* __restrict__ C, int N) {
  __shared__ unsigned short As_hi[64][40];    // stride 80B: 16B-aligned, ~2-way banks
  __shared__ unsigned short As_lo[64][40];
  __shared__ unsigned short Bs_hi[256][40];   // [col][k]
  __shared__ unsigned short Bs_lo[256][40];
  int t = threadIdx.x;
  int row0 = blockIdx.x * 64;
  int lane = t & 63;
  int col0 = (t >> 6) * 64;     // wave's column quadrant
  int frow = lane & 15;
  int fk8  = lane >> 4;

  f32x4 acc[4][4];
#pragma unroll
  for (int i = 0; i < 4; ++i)
#pragma unroll
    for (int j = 0; j < 4; ++j)
#pragma unroll
      for (int q = 0; q < 4; ++q) acc[i][j][q] = 0.f;

  for (int k0 = 0; k0 < 256; k0 += 32) {
    // stage A: 64 rows x 32 k fp32 -> split bf16 hi/lo
    {
      int r = t >> 3;             // 0..31
      int kk = (t & 7) * 4;       // element offset, 8 threads x 4 elems = 32 k
#pragma unroll
      for (int rep = 0; rep < 2; ++rep) {
        int rr = r + rep * 32;
        int gr = row0 + rr;
        float4 v = {0.f, 0.f, 0.f, 0.f};
        if (gr < N) v = *(const float4*)&A[(size_t)gr * FIN + k0 + kk];
        unsigned short h0, l0, h1, l1, h2, l2, h3, l3;
        bf16split(v.x, h0, l0); bf16split(v.y, h1, l1);
        bf16split(v.z, h2, l2); bf16split(v.w, h3, l3);
        ushort4 vh = {h0, h1, h2, h3};
        ushort4 vl = {l0, l1, l2, l3};
        *(ushort4*)&As_hi[rr][kk] = vh;
        *(ushort4*)&As_lo[rr][kk] = vl;
      }
    }
    // stage B: thread t = col; copy ALL 32 k (4 x int4 = 4 x 8 shorts) per buffer
    // [R11 fix: int4 = 8 shorts, so step is q*8 elements, q<4 — the R10 version
    //  stepped q*16 with q<2, copying only half the k's from wrong offsets]
    {
#pragma unroll
      for (int q = 0; q < 4; ++q) {
        int4 vh = *(const int4*)&Bt_hi[(size_t)t * FIN + k0 + q * 8];
        int4 vl = *(const int4*)&Bt_lo[(size_t)t * FIN + k0 + q * 8];
        *(int4*)&Bs_hi[t][q * 8] = vh;
        *(int4*)&Bs_lo[t][q * 8] = vl;
      }
    }
    __syncthreads();
    // compute: 16 (rt,ct) tiles x 3 MFMAs
    short8v bh[4], bl[4];
#pragma unroll
    for (int ct = 0; ct < 4; ++ct) {
      bh[ct] = *(const short8v*)&Bs_hi[col0 + ct * 16 + frow][fk8 * 8];
      bl[ct] = *(const short8v*)&Bs_lo[col0 + ct * 16 + frow][fk8 * 8];
    }
#pragma unroll
    for (int rt = 0; rt < 4; ++rt) {
      short8v ah = *(const short8v*)&As_hi[rt * 16 + frow][fk8 * 8];
      short8v al = *(const short8v*)&As_lo[rt * 16 + frow][fk8 * 8];
#pragma unroll
      for (int ct = 0; ct < 4; ++ct) {
        acc[rt][ct] = __builtin_amdgcn_mfma_f32_16x16x32_bf16(ah, bh[ct], acc[rt][ct], 0, 0, 0);
        acc[rt][ct] = __builtin_amdgcn_mfma_f32_16x16x32_bf16(ah, bl[ct], acc[rt][ct], 0, 0, 0);
        acc[rt][ct] = __builtin_amdgcn_mfma_f32_16x16x32_bf16(al, bh[ct], acc[rt][ct], 0, 0, 0);
      }
    }
    __syncthreads();
  }
  // epilogue: D lane mapping col=lane&15, row=fk8*4+i
#pragma unroll
  for (int rt = 0; rt < 4; ++rt) {
#pragma unroll
    for (int i = 0; i < 4; ++i) {
      int gr = row0 + rt * 16 + fk8 * 4 + i;
      if (gr < N) {
#pragma unroll
        for (int ct = 0; ct < 4; ++ct)
          C[(size_t)gr * D1 + col0 + ct * 16 + frow] = __float2half(acc[rt][ct][i]);
      }
    }
  }
}

// ---------------- alpha1: per-node dot with att vectors (fp16 h) ----------------
__global__ __launch_bounds__(256) void alpha1_kernel(const __half* __restrict__ h,
                                                     const float* __restrict__ a_src,
                                                     const float* __restrict__ a_dst,
                                                     float* __restrict__ as,
                                                     float* __restrict__ ad, int N) {
  int wid = (blockIdx.x * blockDim.x + threadIdx.x) >> 6;
  if (wid >= N) return;
  int lane = threadIdx.x & 63;
  int2 r = *(const int2*)&h[(size_t)wid * D1 + lane * 4];
  float2 f01 = __half22float2(*(__half2*)&r.x);
  float2 f23 = __half22float2(*(__half2*)&r.y);
  float4 s4 = *(const float4*)&a_src[lane * 4];
  float4 d4 = *(const float4*)&a_dst[lane * 4];
  float ps = f01.x * s4.x + f01.y * s4.y + f23.x * s4.z + f23.y * s4.w;
  float pd = f01.x * d4.x + f01.y * d4.y + f23.x * d4.z + f23.y * d4.w;
#pragma unroll
  for (int off = 8; off >= 1; off >>= 1) {
    ps += __shfl_xor(ps, off);
    pd += __shfl_xor(pd, off);
  }
  int hh = lane >> 4;
  if ((lane & 15) == 0) { as[wid * 4 + hh] = ps; ad[wid * 4 + hh] = pd; }
}

// ---------------- stats1: per-(node,head) online softmax stats ----------------
__global__ __launch_bounds__(256) void stats1_kernel(const float* __restrict__ as1,
                                                     const float* __restrict__ ad1,
                                                     const int* __restrict__ row_ptr,
                                                     const int* __restrict__ col,
                                                     float* __restrict__ mx1,
                                                     float* __restrict__ inv1, int N) {
  int t = blockIdx.x * blockDim.x + threadIdx.x;
  if (t >= N * 4) return;
  int n = t >> 2, h = t & 3;
  int beg = row_ptr[n];
  int deg = row_ptr[n + 1] - beg;
  float adh = ad1[t];
  float m = -INFINITY, s = 0.f;
  int cn = col[beg];
  for (int j = 0; j < deg; ++j) {
    int c = cn;
    if (j + 1 < deg) cn = col[beg + j + 1];
    float e = lrelu(as1[(size_t)c * 4 + h] + adh);
    float nm = fmaxf(m, e);
    s = s * expf(m - nm) + expf(e - nm);
    m = nm;
  }
  mx1[t] = m;
  inv1[t] = 1.f / (s + 1e-16f);
}

// ---------------- agg1: weighted aggregate, fp16 gather, 4-deep loads ----------------
__global__ __launch_bounds__(256) void agg1_kernel(const __half* __restrict__ hl,
                                                   const float* __restrict__ as1,
                                                   const float* __restrict__ ad1,
                                                   const float* __restrict__ mx1,
                                                   const float* __restrict__ inv1,
                                                   const int* __restrict__ row_ptr,
                                                   const int* __restrict__ col,
                                                   const float* __restrict__ b1,
                                                   float* __restrict__ h1, int N) {
  int wid = (blockIdx.x * blockDim.x + threadIdx.x) >> 6;
  if (wid >= N) return;
  int lane = threadIdx.x & 63;
  int hm = lane >> 4;
  int beg = row_ptr[wid];
  int deg = row_ptr[wid + 1] - beg;
  float adh = ad1[wid * 4 + hm];
  float mh  = mx1[wid * 4 + hm];
  float ih  = inv1[wid * 4 + hm];
  float4 acc = {0.f, 0.f, 0.f, 0.f};
  int j = 0;
  for (; j + 4 <= deg; j += 4) {
    int s0 = col[beg + j + 0];
    int s1 = col[beg + j + 1];
    int s2 = col[beg + j + 2];
    int s3 = col[beg + j + 3];
    float a0 = as1[(size_t)s0 * 4 + hm];
    float a1 = as1[(size_t)s1 * 4 + hm];
    float a2 = as1[(size_t)s2 * 4 + hm];
    float a3 = as1[(size_t)s3 * 4 + hm];
    int2 r0 = *(const int2*)&hl[(size_t)s0 * D1 + lane * 4];
    int2 r1 = *(const int2*)&hl[(size_t)s1 * D1 + lane * 4];
    int2 r2 = *(const int2*)&hl[(size_t)s2 * D1 + lane * 4];
    int2 r3 = *(const int2*)&hl[(size_t)s3 * D1 + lane * 4];
    float w0 = expf(lrelu(a0 + adh) - mh) * ih;
    float w1 = expf(lrelu(a1 + adh) - mh) * ih;
    float w2 = expf(lrelu(a2 + adh) - mh) * ih;
    float w3 = expf(lrelu(a3 + adh) - mh) * ih;
    float2 u, v;
    u = __half22float2(*(__half2*)&r0.x); v = __half22float2(*(__half2*)&r0.y);
    acc.x = fmaf(w0, u.x, acc.x); acc.y = fmaf(w0, u.y, acc.y);
    acc.z = fmaf(w0, v.x, acc.z); acc.w = fmaf(w0, v.y, acc.w);
    u = __half22float2(*(__half2*)&r1.x); v = __half22float2(*(__half2*)&r1.y);
    acc.x = fmaf(w1, u.x, acc.x); acc.y = fmaf(w1, u.y, acc.y);
    acc.z = fmaf(w1, v.x, acc.z); acc.w = fmaf(w1, v.y, acc.w);
    u = __half22float2(*(__half2*)&r2.x); v = __half22float2(*(__half2*)&r2.y);
    acc.x = fmaf(w2, u.x, acc.x); acc.y = fmaf(w2, u.y, acc.y);
    acc.z = fmaf(w2, v.x, acc.z); acc.w = fmaf(w2, v.y, acc.w);
    u = __half22float2(*(__half2*)&r3.x); v = __half22float2(*(__half2*)&r3.y);
    acc.x = fmaf(w3, u.x, acc.x); acc.y = fmaf(w3, u.y, acc.y);
    acc.z = fmaf(w3, v.x, acc.z); acc.w = fmaf(w3, v.y, acc.w);
  }
  for (; j < deg; ++j) {
    int s0 = col[beg + j];
    float a0 = as1[(size_t)s0 * 4 + hm];
    int2 r0 = *(const int2*)&hl[(size_t)s0 * D1 + lane * 4];
    float w0 = expf(lrelu(a0 + adh) - mh) * ih;
    float2 u = __half22float2(*(__half2*)&r0.x);
    float2 v = __half22float2(*(__half2*)&r0.y);
    acc.x = fmaf(w0, u.x, acc.x); acc.y = fmaf(w0, u.y, acc.y);
    acc.z = fmaf(w0, v.x, acc.z); acc.w = fmaf(w0, v.y, acc.w);
  }
  float4 bb = *(const float4*)&b1[lane * 4];
  float4 o;
  o.x = fmaxf(acc.x + bb.x, 0.f);
  o.y = fmaxf(acc.y + bb.y, 0.f);
  o.z = fmaxf(acc.z + bb.z, 0.f);
  o.w = fmaxf(acc.w + bb.w, 0.f);
  *(float4*)&h1[(size_t)wid * D1 + lane * 4] = o;
}

// ---------------- GEMM2: fp32 [N,256] @ [256,32] -> fp16 [N,32] ----------------
__global__ __launch_bounds__(256) void gemm2_kernel(const float* __restrict__ A,
                                                    const float* __restrict__ B,
                                                    __half* __restrict__ C, int N) {
  __shared__ float ws[256][33];   // full W2
  __shared__ float xs[32][132];   // transposed A chunk
  int t = threadIdx.x;
#pragma unroll
  for (int j = 0; j < 32; ++j) {
    int idx = j * 256 + t;
    ws[idx >> 5][idx & 31] = B[idx];
  }
  int row0 = blockIdx.x * 128;
  int tx = t & 31, ty = t >> 5;
  float acc[16] = {};
  for (int k0 = 0; k0 < 256; k0 += 32) {
    __syncthreads();
#pragma unroll
    for (int rep = 0; rep < 4; ++rep) {
      int r = (t >> 3) + rep * 32;
      int kk = (t & 7) * 4;
      int gr = row0 + r;
      float4 v = {0.f, 0.f, 0.f, 0.f};
      if (gr < N) v = *(const float4*)&A[(size_t)gr * D1 + k0 + kk];
      xs[kk + 0][r] = v.x; xs[kk + 1][r] = v.y; xs[kk + 2][r] = v.z; xs[kk + 3][r] = v.w;
    }
    __syncthreads();
#pragma unroll
    for (int k = 0; k < 32; ++k) {
      float w = ws[k0 + k][tx];
#pragma unroll
      for (int rq = 0; rq < 4; ++rq) {
        float4 a4 = *(const float4*)&xs[k][ty * 16 + rq * 4];
        acc[rq * 4 + 0] = fmaf(a4.x, w, acc[rq * 4 + 0]);
        acc[rq * 4 + 1] = fmaf(a4.y, w, acc[rq * 4 + 1]);
        acc[rq * 4 + 2] = fmaf(a4.z, w, acc[rq * 4 + 2]);
        acc[rq * 4 + 3] = fmaf(a4.w, w, acc[rq * 4 + 3]);
      }
    }
  }
#pragma unroll
  for (int j = 0; j < 16; ++j) {
    int gr = row0 + ty * 16 + j;
    if (gr < N) C[(size_t)gr * DOUT + tx] = __float2half(acc[j]);
  }
}

// ---------------- alpha2: one wave handles two nodes (fp16 h2) ----------------
__global__ __launch_bounds__(256) void alpha2_kernel(const __half* __restrict__ h2,
                                                     const float* __restrict__ a_src,
                                                     const float* __restrict__ a_dst,
                                                     float* __restrict__ as,
                                                     float* __restrict__ ad, int N) {
  int wid = (blockIdx.x * blockDim.x + threadIdx.x) >> 6;
  int lane = threadIdx.x & 63;
  int n = wid * 2 + (lane >> 5);
  int c = lane & 31;
  float v = (n < N) ? __half2float(h2[(size_t)n * DOUT + c]) : 0.f;
  float ps = v * a_src[c];
  float pd = v * a_dst[c];
#pragma unroll
  for (int off = 16; off >= 1; off >>= 1) {
    ps += __shfl_xor(ps, off);
    pd += __shfl_xor(pd, off);
  }
  if (c == 0 && n < N) { as[n] = ps; ad[n] = pd; }
}

// ---------------- stats2: per-node online softmax stats (H=1) ----------------
__global__ __launch_bounds__(256) void stats2_kernel(const float* __restrict__ as2,
                                                     const float* __restrict__ ad2,
                                                     const int* __restrict__ row_ptr,
                                                     const int* __restrict__ col,
                                                     float* __restrict__ mx2,
                                                     float* __restrict__ inv2, int N) {
  int n = blockIdx.x * blockDim.x + threadIdx.x;
  if (n >= N) return;
  int beg = row_ptr[n];
  int deg = row_ptr[n + 1] - beg;
  float ad = ad2[n];
  float m = -INFINITY, s = 0.f;
  int cn = col[beg];
  for (int j = 0; j < deg; ++j) {
    int c = cn;
    if (j + 1 < deg) cn = col[beg + j + 1];
    float e = lrelu(as2[c] + ad);
    float nm = fmaxf(m, e);
    s = s * expf(m - nm) + expf(e - nm);
    m = nm;
  }
  mx2[n] = m;
  inv2[n] = 1.f / (s + 1e-16f);
}

// ---------------- agg2: weighted aggregate (H=1, C=32), fp16 gather ----------------
__global__ __launch_bounds__(256) void agg2_kernel(const __half* __restrict__ h2,
                                                   const float* __restrict__ as2,
                                                   const float* __restrict__ ad2,
                                                   const float* __restrict__ mx2,
                                                   const float* __restrict__ inv2,
                                                   const int* __restrict__ row_ptr,
                                                   const int* __restrict__ col,
                                                   const float* __restrict__ b2,
                                                   float* __restrict__ out, int N) {
  int wid = (blockIdx.x * blockDim.x + threadIdx.x) >> 6;
  if (wid >= N) return;
  int lane = threadIdx.x & 63;
  int c = lane & 31;
  int beg = row_ptr[wid];
  int deg = row_ptr[wid + 1] - beg;
  float ad = ad2[wid];
  float mh = mx2[wid];
  float ih = inv2[wid];
  float acc = 0.f;
  int j = 0;
  for (; j + 4 <= deg; j += 4) {
    int s0 = col[beg + j + 0];
    int s1 = col[beg + j + 1];
    int s2 = col[beg + j + 2];
    int s3 = col[beg + j + 3];
    float a0 = as2[s0];
    float a1 = as2[s1];
    float a2 = as2[s2];
    float a3 = as2[s3];
    float v0 = __half2float(h2[(size_t)s0 * DOUT + c]);
    float v1 = __half2float(h2[(size_t)s1 * DOUT + c]);
    float v2 = __half2float(h2[(size_t)s2 * DOUT + c]);
    float v3 = __half2float(h2[(size_t)s3 * DOUT + c]);
    float w0 = expf(lrelu(a0 + ad) - mh) * ih;
    float w1 = expf(lrelu(a1 + ad) - mh) * ih;
    float w2 = expf(lrelu(a2 + ad) - mh) * ih;
    float w3 = expf(lrelu(a3 + ad) - mh) * ih;
    acc = fmaf(w0, v0, acc);
    acc = fmaf(w1, v1, acc);
    acc = fmaf(w2, v2, acc);
    acc = fmaf(w3, v3, acc);
  }
  for (; j < deg; ++j) {
    int s0 = col[beg + j];
    float a0 = as2[s0];
    float v0 = __half2float(h2[(size_t)s0 * DOUT + c]);
    float w0 = expf(lrelu(a0 + ad) - mh) * ih;
    acc = fmaf(w0, v0, acc);
  }
  if (lane < 32) out[(size_t)wid * DOUT + c] = acc + b2[c];
}

// ---------------- launch ----------------
extern "C" void kernel_launch(void* const* d_in, const int* in_sizes, int n_in,
                              void* d_out, int out_size, void* d_ws, size_t ws_size,
                              hipStream_t stream) {
  const float* x     = (const float*)d_in[0];
  const int*   ei    = (const int*)d_in[1];
  const float* W1    = (const float*)d_in[2];
  const float* asrc1 = (const float*)d_in[3];
  const float* adst1 = (const float*)d_in[4];
  const float* b1    = (const float*)d_in[5];
  const float* W2    = (const float*)d_in[6];
  const float* asrc2 = (const float*)d_in[7];
  const float* adst2 = (const float*)d_in[8];
  const float* b2    = (const float*)d_in[9];

  const int N = in_sizes[0] / FIN;
  const int E = in_sizes[1] / 2;
  const int ET = E + N;
  const int* src = ei;
  const int* dst = ei + E;

  char* base = (char*)d_ws;
  size_t off = 0;
  auto alloc = [&](size_t bytes) -> void* {
    void* p = base + off;
    off = (off + bytes + 255) & ~(size_t)255;
    return p;
  };
  int* row_ptr = (int*)alloc((size_t)(N + 1) * 4);
  int* deg     = (int*)alloc((size_t)N * 4);
  int* cur     = (int*)alloc((size_t)N * 4);
  int* col     = (int*)alloc((size_t)ET * 4);
  float* as1   = (float*)alloc((size_t)N * 4 * 4);
  float* ad1   = (float*)alloc((size_t)N * 4 * 4);
  float* mx1   = (float*)alloc((size_t)N * 4 * 4);
  float* inv1  = (float*)alloc((size_t)N * 4 * 4);
  float* as2   = (float*)alloc((size_t)N * 4);
  float* ad2   = (float*)alloc((size_t)N * 4);
  float* mx2   = (float*)alloc((size_t)N * 4);
  float* inv2  = (float*)alloc((size_t)N * 4);
  unsigned short* Wt_hi = (unsigned short*)alloc((size_t)FIN * D1 * 2);
  unsigned short* Wt_lo = (unsigned short*)alloc((size_t)FIN * D1 * 2);
  __half* hl1  = (__half*)alloc((size_t)N * D1 * 2);   // fp16 gather source L1
  float* h1    = (float*)alloc((size_t)N * D1 * 4);    // fp32, streamed by gemm2
  __half* h2   = hl1;   // reuse: hl1 dead after agg1
  float* out   = (float*)d_out;

  // CSR build (shared by both layers) + W1 split (independent)
  hipLaunchKernelGGL(zero2_kernel, dim3((N + 255) / 256), dim3(256), 0, stream, deg, cur, N);
  hipLaunchKernelGGL(count_kernel, dim3((ET + 255) / 256), dim3(256), 0, stream, src, dst, deg, E, N);
  hipLaunchKernelGGL(splitW1_kernel, dim3(FIN * D1 / 256), dim3(256), 0, stream, W1, Wt_hi, Wt_lo);
  hipLaunchKernelGGL(scan_kernel, dim3(1), dim3(1024), 0, stream, deg, row_ptr, N);
  hipLaunchKernelGGL(scatter_kernel, dim3((ET + 255) / 256), dim3(256), 0, stream, src, dst, row_ptr, cur, col, E, N);

  // layer 1
  hipLaunchKernelGGL(gemm1_kernel, dim3((N + 63) / 64), dim3(256), 0, stream, x, Wt_hi, Wt_lo, hl1, N);
  hipLaunchKernelGGL(alpha1_kernel, dim3((N + 3) / 4), dim3(256), 0, stream, hl1, asrc1, adst1, as1, ad1, N);
  hipLaunchKernelGGL(stats1_kernel, dim3((N * 4 + 255) / 256), dim3(256), 0, stream, as1, ad1, row_ptr, col, mx1, inv1, N);
  hipLaunchKernelGGL(agg1_kernel, dim3((N + 3) / 4), dim3(256), 0, stream, hl1, as1, ad1, mx1, inv1, row_ptr, col, b1, h1, N);

  // layer 2
  hipLaunchKernelGGL(gemm2_kernel, dim3((N + 127) / 128), dim3(256), 0, stream, h1, W2, h2, N);
  hipLaunchKernelGGL(alpha2_kernel, dim3((N + 7) / 8), dim3(256), 0, stream, h2, asrc2, adst2, as2, ad2, N);
  hipLaunchKernelGGL(stats2_kernel, dim3((N + 255) / 256), dim3(256), 0, stream, as2, ad2, row_ptr, col, mx2, inv2, N);
  hipLaunchKernelGGL(agg2_kernel, dim3((N + 3) / 4), dim3(256), 0, stream, h2, as2, ad2, mx2, inv2, row_ptr, col, b2, out, N);
}

// Round 13
// 410.935 us; speedup vs baseline: 2.0466x; 1.1983x over previous
//
#include <hip/hip_runtime.h>
#include <hip/hip_fp16.h>
#include <math.h>

// Problem constants (from reference): F_in=256, H=4, HID=64 -> D1=256, OUT=32
#define FIN  256
#define D1   256
#define NHEAD 4
#define HIDC 64
#define DOUT 32
#define NSLOPE 0.2f
#define SCHUNK 2048   // scan: elements per block (256 thr x 8)

typedef __attribute__((ext_vector_type(8))) short short8v;   // 8 bf16 = 4 VGPR
typedef __attribute__((ext_vector_type(4))) float f32x4;     // MFMA acc

__device__ __forceinline__ float lrelu(float x) { return x >= 0.f ? x : NSLOPE * x; }

// round-to-nearest-even fp32 -> bf16 split: x ~= hi + lo (both bf16)
__device__ __forceinline__ void bf16split(float x, unsigned short& h, unsigned short& l) {
  unsigned u = __float_as_uint(x);
  unsigned uh = (u + 0x7fffu + ((u >> 16) & 1u)) & 0xffff0000u;
  h = (unsigned short)(uh >> 16);
  float r = x - __uint_as_float(uh);
  unsigned ur = __float_as_uint(r);
  l = (unsigned short)((ur + 0x7fffu + ((ur >> 16) & 1u)) >> 16);
}

// ---------------- CSR construction ----------------
__global__ void zero2_kernel(int* __restrict__ a, int* __restrict__ b, int n) {
  int i = blockIdx.x * blockDim.x + threadIdx.x;
  if (i < n) { a[i] = 0; b[i] = 0; }
}

__global__ void count_kernel(const int* __restrict__ src, const int* __restrict__ dst,
                             int* __restrict__ deg, int E, int N) {
  int i = blockIdx.x * blockDim.x + threadIdx.x;
  if (i < E) {
    atomicAdd(&deg[dst[i]], 1);
  } else if (i < E + N) {
    atomicAdd(&deg[i - E], 1);   // self-loop
  }
}

// ---- hierarchical scan (R12: replaces 80µs single-block scan) ----
// pass1: per-block sums of 2048-int chunks
__global__ __launch_bounds__(256) void scan1_kernel(const int* __restrict__ deg,
                                                    int* __restrict__ bsum, int N) {
  int b = blockIdx.x, t = threadIdx.x;
  int base = b * SCHUNK + t * 8;
  int s = 0;
  if (base + 8 <= N) {
    int4 a = *(const int4*)&deg[base];
    int4 c = *(const int4*)&deg[base + 4];
    s = a.x + a.y + a.z + a.w + c.x + c.y + c.z + c.w;
  } else {
#pragma unroll
    for (int i = 0; i < 8; ++i) if (base + i < N) s += deg[base + i];
  }
  int lane = t & 63, w = t >> 6;
#pragma unroll
  for (int off = 32; off >= 1; off >>= 1) s += __shfl_down(s, off);
  __shared__ int sh[4];
  if (lane == 0) sh[w] = s;
  __syncthreads();
  if (t == 0) bsum[b] = sh[0] + sh[1] + sh[2] + sh[3];
}

// pass2: single-block inclusive scan over block sums (nb <= 1024)
__global__ __launch_bounds__(1024) void scan2_kernel(int* __restrict__ bsum, int nb) {
  __shared__ int sh[1024];
  int t = threadIdx.x;
  sh[t] = (t < nb) ? bsum[t] : 0;
  __syncthreads();
  for (int off = 1; off < 1024; off <<= 1) {
    int u = (t >= off) ? sh[t - off] : 0;
    __syncthreads();
    sh[t] += u;
    __syncthreads();
  }
  if (t < nb) bsum[t] = sh[t];   // inclusive prefix
}

// pass3: rescan chunk with global offset, write row_ptr[i+1]
__global__ __launch_bounds__(256) void scan3_kernel(const int* __restrict__ deg,
                                                    const int* __restrict__ bsum,
                                                    int* __restrict__ row_ptr, int N) {
  int b = blockIdx.x, t = threadIdx.x;
  int base = b * SCHUNK + t * 8;
  int vals[8];
  if (base + 8 <= N) {
    int4 a = *(const int4*)&deg[base];
    int4 c = *(const int4*)&deg[base + 4];
    vals[0] = a.x; vals[1] = a.y; vals[2] = a.z; vals[3] = a.w;
    vals[4] = c.x; vals[5] = c.y; vals[6] = c.z; vals[7] = c.w;
  } else {
#pragma unroll
    for (int i = 0; i < 8; ++i) vals[i] = (base + i < N) ? deg[base + i] : 0;
  }
  int s = 0;
#pragma unroll
  for (int i = 0; i < 8; ++i) { s += vals[i]; vals[i] = s; }   // thread-local inclusive
  // block scan of per-thread totals: wave shfl_up + LDS wave offsets
  int lane = t & 63, w = t >> 6;
  int inc = s;
#pragma unroll
  for (int off = 1; off < 64; off <<= 1) {
    int u = __shfl_up(inc, off);
    if (lane >= off) inc += u;
  }
  __shared__ int wsum[4];
  if (lane == 63) wsum[w] = inc;
  __syncthreads();
  int woff = 0;
#pragma unroll
  for (int i = 0; i < 4; ++i) if (i < w) woff += wsum[i];
  int excl = woff + inc - s;                       // exclusive prefix of this thread
  int offbase = (b ? bsum[b - 1] : 0) + excl;
#pragma unroll
  for (int i = 0; i < 8; ++i) {
    int idx = base + i;
    if (idx < N) row_ptr[idx + 1] = offbase + vals[i];
  }
  if (b == 0 && t == 0) row_ptr[0] = 0;
}

__global__ void scatter_kernel(const int* __restrict__ src, const int* __restrict__ dst,
                               const int* __restrict__ row_ptr, int* __restrict__ cur,
                               int* __restrict__ col, int E, int N) {
  int i = blockIdx.x * blockDim.x + threadIdx.x;
  int s, d;
  if (i < E) { s = src[i]; d = dst[i]; }
  else if (i < E + N) { s = i - E; d = i - E; }
  else return;
  int pos = row_ptr[d] + atomicAdd(&cur[d], 1);
  col[pos] = s;
}

// ---------------- W1 split+transpose: W1[k][c] -> Wt_hi/lo[c][k] (bf16) ----------------
__global__ __launch_bounds__(256) void splitW1_kernel(const float* __restrict__ W1,
                                                      unsigned short* __restrict__ Wt_hi,
                                                      unsigned short* __restrict__ Wt_lo) {
  int t = blockIdx.x * 256 + threadIdx.x;   // 65536 threads
  int c = t >> 8, k = t & 255;              // write coalesced over k
  float x = W1[(size_t)k * D1 + c];
  unsigned short h, l;
  bf16split(x, h, l);
  Wt_hi[(size_t)c * FIN + k] = h;
  Wt_lo[(size_t)c * FIN + k] = l;
}

// ---------------- GEMM1 (MFMA split-bf16): [N,256] @ [256,256] -> fp16 ----------------
__global__ __launch_bounds__(256) void gemm1_kernel(const float* __restrict__ A,
                                                    const unsigned short* __restrict__ Bt_hi,
                                                    const unsigned short* __restrict__ Bt_lo,
                                                    __half* __restrict__ C, int N) {
  __shared__ unsigned short As_hi[64][40];    // stride 80B: 16B-aligned, ~2-way banks
  __shared__ unsigned short As_lo[64][40];
  __shared__ unsigned short Bs_hi[256][40];   // [col][k]
  __shared__ unsigned short Bs_lo[256][40];
  int t = threadIdx.x;
  int row0 = blockIdx.x * 64;
  int lane = t & 63;
  int col0 = (t >> 6) * 64;     // wave's column quadrant
  int frow = lane & 15;
  int fk8  = lane >> 4;

  f32x4 acc[4][4];
#pragma unroll
  for (int i = 0; i < 4; ++i)
#pragma unroll
    for (int j = 0; j < 4; ++j)
#pragma unroll
      for (int q = 0; q < 4; ++q) acc[i][j][q] = 0.f;

  for (int k0 = 0; k0 < 256; k0 += 32) {
    // stage A: 64 rows x 32 k fp32 -> split bf16 hi/lo
    {
      int r = t >> 3;             // 0..31
      int kk = (t & 7) * 4;       // element offset, 8 threads x 4 elems = 32 k
#pragma unroll
      for (int rep = 0; rep < 2; ++rep) {
        int rr = r + rep * 32;
        int gr = row0 + rr;
        float4 v = {0.f, 0.f, 0.f, 0.f};
        if (gr < N) v = *(const float4*)&A[(size_t)gr * FIN + k0 + kk];
        unsigned short h0, l0, h1, l1, h2, l2, h3, l3;
        bf16split(v.x, h0, l0); bf16split(v.y, h1, l1);
        bf16split(v.z, h2, l2); bf16split(v.w, h3, l3);
        ushort4 vh = {h0, h1, h2, h3};
        ushort4 vl = {l0, l1, l2, l3};
        *(ushort4*)&As_hi[rr][kk] = vh;
        *(ushort4*)&As_lo[rr][kk] = vl;
      }
    }
    // stage B: thread t = col; copy ALL 32 k (4 x int4 = 4 x 8 shorts) per buffer
    {
#pragma unroll
      for (int q = 0; q < 4; ++q) {
        int4 vh = *(const int4*)&Bt_hi[(size_t)t * FIN + k0 + q * 8];
        int4 vl = *(const int4*)&Bt_lo[(size_t)t * FIN + k0 + q * 8];
        *(int4*)&Bs_hi[t][q * 8] = vh;
        *(int4*)&Bs_lo[t][q * 8] = vl;
      }
    }
    __syncthreads();
    // compute: 16 (rt,ct) tiles x 3 MFMAs
    short8v bh[4], bl[4];
#pragma unroll
    for (int ct = 0; ct < 4; ++ct) {
      bh[ct] = *(const short8v*)&Bs_hi[col0 + ct * 16 + frow][fk8 * 8];
      bl[ct] = *(const short8v*)&Bs_lo[col0 + ct * 16 + frow][fk8 * 8];
    }
#pragma unroll
    for (int rt = 0; rt < 4; ++rt) {
      short8v ah = *(const short8v*)&As_hi[rt * 16 + frow][fk8 * 8];
      short8v al = *(const short8v*)&As_lo[rt * 16 + frow][fk8 * 8];
#pragma unroll
      for (int ct = 0; ct < 4; ++ct) {
        acc[rt][ct] = __builtin_amdgcn_mfma_f32_16x16x32_bf16(ah, bh[ct], acc[rt][ct], 0, 0, 0);
        acc[rt][ct] = __builtin_amdgcn_mfma_f32_16x16x32_bf16(ah, bl[ct], acc[rt][ct], 0, 0, 0);
        acc[rt][ct] = __builtin_amdgcn_mfma_f32_16x16x32_bf16(al, bh[ct], acc[rt][ct], 0, 0, 0);
      }
    }
    __syncthreads();
  }
  // epilogue: D lane mapping col=lane&15, row=fk8*4+i
#pragma unroll
  for (int rt = 0; rt < 4; ++rt) {
#pragma unroll
    for (int i = 0; i < 4; ++i) {
      int gr = row0 + rt * 16 + fk8 * 4 + i;
      if (gr < N) {
#pragma unroll
        for (int ct = 0; ct < 4; ++ct)
          C[(size_t)gr * D1 + col0 + ct * 16 + frow] = __float2half(acc[rt][ct][i]);
      }
    }
  }
}

// ---------------- alpha1: per-node dot with att vectors (fp16 h) ----------------
__global__ __launch_bounds__(256) void alpha1_kernel(const __half* __restrict__ h,
                                                     const float* __restrict__ a_src,
                                                     const float* __restrict__ a_dst,
                                                     float* __restrict__ as,
                                                     float* __restrict__ ad, int N) {
  int wid = (blockIdx.x * blockDim.x + threadIdx.x) >> 6;
  if (wid >= N) return;
  int lane = threadIdx.x & 63;
  int2 r = *(const int2*)&h[(size_t)wid * D1 + lane * 4];
  float2 f01 = __half22float2(*(__half2*)&r.x);
  float2 f23 = __half22float2(*(__half2*)&r.y);
  float4 s4 = *(const float4*)&a_src[lane * 4];
  float4 d4 = *(const float4*)&a_dst[lane * 4];
  float ps = f01.x * s4.x + f01.y * s4.y + f23.x * s4.z + f23.y * s4.w;
  float pd = f01.x * d4.x + f01.y * d4.y + f23.x * d4.z + f23.y * d4.w;
#pragma unroll
  for (int off = 8; off >= 1; off >>= 1) {
    ps += __shfl_xor(ps, off);
    pd += __shfl_xor(pd, off);
  }
  int hh = lane >> 4;
  if ((lane & 15) == 0) { as[wid * 4 + hh] = ps; ad[wid * 4 + hh] = pd; }
}

// ---------------- stats1: per-(node,head) online softmax stats ----------------
__global__ __launch_bounds__(256) void stats1_kernel(const float* __restrict__ as1,
                                                     const float* __restrict__ ad1,
                                                     const int* __restrict__ row_ptr,
                                                     const int* __restrict__ col,
                                                     float* __restrict__ mx1,
                                                     float* __restrict__ inv1, int N) {
  int t = blockIdx.x * blockDim.x + threadIdx.x;
  if (t >= N * 4) return;
  int n = t >> 2, h = t & 3;
  int beg = row_ptr[n];
  int deg = row_ptr[n + 1] - beg;
  float adh = ad1[t];
  float m = -INFINITY, s = 0.f;
  int cn = col[beg];
  for (int j = 0; j < deg; ++j) {
    int c = cn;
    if (j + 1 < deg) cn = col[beg + j + 1];
    float e = lrelu(as1[(size_t)c * 4 + h] + adh);
    float nm = fmaxf(m, e);
    s = s * expf(m - nm) + expf(e - nm);
    m = nm;
  }
  mx1[t] = m;
  inv1[t] = 1.f / (s + 1e-16f);
}

// ---------------- agg1: weighted aggregate, fp16 gather, 4-deep loads ----------------
__global__ __launch_bounds__(256) void agg1_kernel(const __half* __restrict__ hl,
                                                   const float* __restrict__ as1,
                                                   const float* __restrict__ ad1,
                                                   const float* __restrict__ mx1,
                                                   const float* __restrict__ inv1,
                                                   const int* __restrict__ row_ptr,
                                                   const int* __restrict__ col,
                                                   const float* __restrict__ b1,
                                                   float* __restrict__ h1, int N) {
  int wid = (blockIdx.x * blockDim.x + threadIdx.x) >> 6;
  if (wid >= N) return;
  int lane = threadIdx.x & 63;
  int hm = lane >> 4;
  int beg = row_ptr[wid];
  int deg = row_ptr[wid + 1] - beg;
  float adh = ad1[wid * 4 + hm];
  float mh  = mx1[wid * 4 + hm];
  float ih  = inv1[wid * 4 + hm];
  float4 acc = {0.f, 0.f, 0.f, 0.f};
  int j = 0;
  for (; j + 4 <= deg; j += 4) {
    int s0 = col[beg + j + 0];
    int s1 = col[beg + j + 1];
    int s2 = col[beg + j + 2];
    int s3 = col[beg + j + 3];
    float a0 = as1[(size_t)s0 * 4 + hm];
    float a1 = as1[(size_t)s1 * 4 + hm];
    float a2 = as1[(size_t)s2 * 4 + hm];
    float a3 = as1[(size_t)s3 * 4 + hm];
    int2 r0 = *(const int2*)&hl[(size_t)s0 * D1 + lane * 4];
    int2 r1 = *(const int2*)&hl[(size_t)s1 * D1 + lane * 4];
    int2 r2 = *(const int2*)&hl[(size_t)s2 * D1 + lane * 4];
    int2 r3 = *(const int2*)&hl[(size_t)s3 * D1 + lane * 4];
    float w0 = expf(lrelu(a0 + adh) - mh) * ih;
    float w1 = expf(lrelu(a1 + adh) - mh) * ih;
    float w2 = expf(lrelu(a2 + adh) - mh) * ih;
    float w3 = expf(lrelu(a3 + adh) - mh) * ih;
    float2 u, v;
    u = __half22float2(*(__half2*)&r0.x); v = __half22float2(*(__half2*)&r0.y);
    acc.x = fmaf(w0, u.x, acc.x); acc.y = fmaf(w0, u.y, acc.y);
    acc.z = fmaf(w0, v.x, acc.z); acc.w = fmaf(w0, v.y, acc.w);
    u = __half22float2(*(__half2*)&r1.x); v = __half22float2(*(__half2*)&r1.y);
    acc.x = fmaf(w1, u.x, acc.x); acc.y = fmaf(w1, u.y, acc.y);
    acc.z = fmaf(w1, v.x, acc.z); acc.w = fmaf(w1, v.y, acc.w);
    u = __half22float2(*(__half2*)&r2.x); v = __half22float2(*(__half2*)&r2.y);
    acc.x = fmaf(w2, u.x, acc.x); acc.y = fmaf(w2, u.y, acc.y);
    acc.z = fmaf(w2, v.x, acc.z); acc.w = fmaf(w2, v.y, acc.w);
    u = __half22float2(*(__half2*)&r3.x); v = __half22float2(*(__half2*)&r3.y);
    acc.x = fmaf(w3, u.x, acc.x); acc.y = fmaf(w3, u.y, acc.y);
    acc.z = fmaf(w3, v.x, acc.z); acc.w = fmaf(w3, v.y, acc.w);
  }
  for (; j < deg; ++j) {
    int s0 = col[beg + j];
    float a0 = as1[(size_t)s0 * 4 + hm];
    int2 r0 = *(const int2*)&hl[(size_t)s0 * D1 + lane * 4];
    float w0 = expf(lrelu(a0 + adh) - mh) * ih;
    float2 u = __half22float2(*(__half2*)&r0.x);
    float2 v = __half22float2(*(__half2*)&r0.y);
    acc.x = fmaf(w0, u.x, acc.x); acc.y = fmaf(w0, u.y, acc.y);
    acc.z = fmaf(w0, v.x, acc.z); acc.w = fmaf(w0, v.y, acc.w);
  }
  float4 bb = *(const float4*)&b1[lane * 4];
  float4 o;
  o.x = fmaxf(acc.x + bb.x, 0.f);
  o.y = fmaxf(acc.y + bb.y, 0.f);
  o.z = fmaxf(acc.z + bb.z, 0.f);
  o.w = fmaxf(acc.w + bb.w, 0.f);
  *(float4*)&h1[(size_t)wid * D1 + lane * 4] = o;
}

// ---------------- GEMM2: fp32 [N,256] @ [256,32] -> fp16 [N,32] ----------------
__global__ __launch_bounds__(256) void gemm2_kernel(const float* __restrict__ A,
                                                    const float* __restrict__ B,
                                                    __half* __restrict__ C, int N) {
  __shared__ float ws[256][33];   // full W2
  __shared__ float xs[32][132];   // transposed A chunk
  int t = threadIdx.x;
#pragma unroll
  for (int j = 0; j < 32; ++j) {
    int idx = j * 256 + t;
    ws[idx >> 5][idx & 31] = B[idx];
  }
  int row0 = blockIdx.x * 128;
  int tx = t & 31, ty = t >> 5;
  float acc[16] = {};
  for (int k0 = 0; k0 < 256; k0 += 32) {
    __syncthreads();
#pragma unroll
    for (int rep = 0; rep < 4; ++rep) {
      int r = (t >> 3) + rep * 32;
      int kk = (t & 7) * 4;
      int gr = row0 + r;
      float4 v = {0.f, 0.f, 0.f, 0.f};
      if (gr < N) v = *(const float4*)&A[(size_t)gr * D1 + k0 + kk];
      xs[kk + 0][r] = v.x; xs[kk + 1][r] = v.y; xs[kk + 2][r] = v.z; xs[kk + 3][r] = v.w;
    }
    __syncthreads();
#pragma unroll
    for (int k = 0; k < 32; ++k) {
      float w = ws[k0 + k][tx];
#pragma unroll
      for (int rq = 0; rq < 4; ++rq) {
        float4 a4 = *(const float4*)&xs[k][ty * 16 + rq * 4];
        acc[rq * 4 + 0] = fmaf(a4.x, w, acc[rq * 4 + 0]);
        acc[rq * 4 + 1] = fmaf(a4.y, w, acc[rq * 4 + 1]);
        acc[rq * 4 + 2] = fmaf(a4.z, w, acc[rq * 4 + 2]);
        acc[rq * 4 + 3] = fmaf(a4.w, w, acc[rq * 4 + 3]);
      }
    }
  }
#pragma unroll
  for (int j = 0; j < 16; ++j) {
    int gr = row0 + ty * 16 + j;
    if (gr < N) C[(size_t)gr * DOUT + tx] = __float2half(acc[j]);
  }
}

// ---------------- alpha2: one wave handles two nodes (fp16 h2) ----------------
__global__ __launch_bounds__(256) void alpha2_kernel(const __half* __restrict__ h2,
                                                     const float* __restrict__ a_src,
                                                     const float* __restrict__ a_dst,
                                                     float* __restrict__ as,
                                                     float* __restrict__ ad, int N) {
  int wid = (blockIdx.x * blockDim.x + threadIdx.x) >> 6;
  int lane = threadIdx.x & 63;
  int n = wid * 2 + (lane >> 5);
  int c = lane & 31;
  float v = (n < N) ? __half2float(h2[(size_t)n * DOUT + c]) : 0.f;
  float ps = v * a_src[c];
  float pd = v * a_dst[c];
#pragma unroll
  for (int off = 16; off >= 1; off >>= 1) {
    ps += __shfl_xor(ps, off);
    pd += __shfl_xor(pd, off);
  }
  if (c == 0 && n < N) { as[n] = ps; ad[n] = pd; }
}

// ---------------- stats2: per-node online softmax stats (H=1) ----------------
__global__ __launch_bounds__(256) void stats2_kernel(const float* __restrict__ as2,
                                                     const float* __restrict__ ad2,
                                                     const int* __restrict__ row_ptr,
                                                     const int* __restrict__ col,
                                                     float* __restrict__ mx2,
                                                     float* __restrict__ inv2, int N) {
  int n = blockIdx.x * blockDim.x + threadIdx.x;
  if (n >= N) return;
  int beg = row_ptr[n];
  int deg = row_ptr[n + 1] - beg;
  float ad = ad2[n];
  float m = -INFINITY, s = 0.f;
  int cn = col[beg];
  for (int j = 0; j < deg; ++j) {
    int c = cn;
    if (j + 1 < deg) cn = col[beg + j + 1];
    float e = lrelu(as2[c] + ad);
    float nm = fmaxf(m, e);
    s = s * expf(m - nm) + expf(e - nm);
    m = nm;
  }
  mx2[n] = m;
  inv2[n] = 1.f / (s + 1e-16f);
}

// ---------------- agg2: weighted aggregate (H=1, C=32), fp16 gather ----------------
__global__ __launch_bounds__(256) void agg2_kernel(const __half* __restrict__ h2,
                                                   const float* __restrict__ as2,
                                                   const float* __restrict__ ad2,
                                                   const float* __restrict__ mx2,
                                                   const float* __restrict__ inv2,
                                                   const int* __restrict__ row_ptr,
                                                   const int* __restrict__ col,
                                                   const float* __restrict__ b2,
                                                   float* __restrict__ out, int N) {
  int wid = (blockIdx.x * blockDim.x + threadIdx.x) >> 6;
  if (wid >= N) return;
  int lane = threadIdx.x & 63;
  int c = lane & 31;
  int beg = row_ptr[wid];
  int deg = row_ptr[wid + 1] - beg;
  float ad = ad2[wid];
  float mh = mx2[wid];
  float ih = inv2[wid];
  float acc = 0.f;
  int j = 0;
  for (; j + 4 <= deg; j += 4) {
    int s0 = col[beg + j + 0];
    int s1 = col[beg + j + 1];
    int s2 = col[beg + j + 2];
    int s3 = col[beg + j + 3];
    float a0 = as2[s0];
    float a1 = as2[s1];
    float a2 = as2[s2];
    float a3 = as2[s3];
    float v0 = __half2float(h2[(size_t)s0 * DOUT + c]);
    float v1 = __half2float(h2[(size_t)s1 * DOUT + c]);
    float v2 = __half2float(h2[(size_t)s2 * DOUT + c]);
    float v3 = __half2float(h2[(size_t)s3 * DOUT + c]);
    float w0 = expf(lrelu(a0 + ad) - mh) * ih;
    float w1 = expf(lrelu(a1 + ad) - mh) * ih;
    float w2 = expf(lrelu(a2 + ad) - mh) * ih;
    float w3 = expf(lrelu(a3 + ad) - mh) * ih;
    acc = fmaf(w0, v0, acc);
    acc = fmaf(w1, v1, acc);
    acc = fmaf(w2, v2, acc);
    acc = fmaf(w3, v3, acc);
  }
  for (; j < deg; ++j) {
    int s0 = col[beg + j];
    float a0 = as2[s0];
    float v0 = __half2float(h2[(size_t)s0 * DOUT + c]);
    float w0 = expf(lrelu(a0 + ad) - mh) * ih;
    acc = fmaf(w0, v0, acc);
  }
  if (lane < 32) out[(size_t)wid * DOUT + c] = acc + b2[c];
}

// ---------------- launch ----------------
extern "C" void kernel_launch(void* const* d_in, const int* in_sizes, int n_in,
                              void* d_out, int out_size, void* d_ws, size_t ws_size,
                              hipStream_t stream) {
  const float* x     = (const float*)d_in[0];
  const int*   ei    = (const int*)d_in[1];
  const float* W1    = (const float*)d_in[2];
  const float* asrc1 = (const float*)d_in[3];
  const float* adst1 = (const float*)d_in[4];
  const float* b1    = (const float*)d_in[5];
  const float* W2    = (const float*)d_in[6];
  const float* asrc2 = (const float*)d_in[7];
  const float* adst2 = (const float*)d_in[8];
  const float* b2    = (const float*)d_in[9];

  const int N = in_sizes[0] / FIN;
  const int E = in_sizes[1] / 2;
  const int ET = E + N;
  const int* src = ei;
  const int* dst = ei + E;
  const int NB = (N + SCHUNK - 1) / SCHUNK;

  char* base = (char*)d_ws;
  size_t off = 0;
  auto alloc = [&](size_t bytes) -> void* {
    void* p = base + off;
    off = (off + bytes + 255) & ~(size_t)255;
    return p;
  };
  int* row_ptr = (int*)alloc((size_t)(N + 1) * 4);
  int* deg     = (int*)alloc((size_t)N * 4);
  int* cur     = (int*)alloc((size_t)N * 4);
  int* col     = (int*)alloc((size_t)ET * 4);
  int* bsum    = (int*)alloc((size_t)1024 * 4);
  float* as1   = (float*)alloc((size_t)N * 4 * 4);
  float* ad1   = (float*)alloc((size_t)N * 4 * 4);
  float* mx1   = (float*)alloc((size_t)N * 4 * 4);
  float* inv1  = (float*)alloc((size_t)N * 4 * 4);
  float* as2   = (float*)alloc((size_t)N * 4);
  float* ad2   = (float*)alloc((size_t)N * 4);
  float* mx2   = (float*)alloc((size_t)N * 4);
  float* inv2  = (float*)alloc((size_t)N * 4);
  unsigned short* Wt_hi = (unsigned short*)alloc((size_t)FIN * D1 * 2);
  unsigned short* Wt_lo = (unsigned short*)alloc((size_t)FIN * D1 * 2);
  __half* hl1  = (__half*)alloc((size_t)N * D1 * 2);   // fp16 gather source L1
  float* h1    = (float*)alloc((size_t)N * D1 * 4);    // fp32, streamed by gemm2
  __half* h2   = hl1;   // reuse: hl1 dead after agg1
  float* out   = (float*)d_out;

  // CSR build (shared by both layers) + W1 split (independent)
  hipLaunchKernelGGL(zero2_kernel, dim3((N + 255) / 256), dim3(256), 0, stream, deg, cur, N);
  hipLaunchKernelGGL(count_kernel, dim3((ET + 255) / 256), dim3(256), 0, stream, src, dst, deg, E, N);
  hipLaunchKernelGGL(splitW1_kernel, dim3(FIN * D1 / 256), dim3(256), 0, stream, W1, Wt_hi, Wt_lo);
  hipLaunchKernelGGL(scan1_kernel, dim3(NB), dim3(256), 0, stream, deg, bsum, N);
  hipLaunchKernelGGL(scan2_kernel, dim3(1), dim3(1024), 0, stream, bsum, NB);
  hipLaunchKernelGGL(scan3_kernel, dim3(NB), dim3(256), 0, stream, deg, bsum, row_ptr, N);
  hipLaunchKernelGGL(scatter_kernel, dim3((ET + 255) / 256), dim3(256), 0, stream, src, dst, row_ptr, cur, col, E, N);

  // layer 1
  hipLaunchKernelGGL(gemm1_kernel, dim3((N + 63) / 64), dim3(256), 0, stream, x, Wt_hi, Wt_lo, hl1, N);
  hipLaunchKernelGGL(alpha1_kernel, dim3((N + 3) / 4), dim3(256), 0, stream, hl1, asrc1, adst1, as1, ad1, N);
  hipLaunchKernelGGL(stats1_kernel, dim3((N * 4 + 255) / 256), dim3(256), 0, stream, as1, ad1, row_ptr, col, mx1, inv1, N);
  hipLaunchKernelGGL(agg1_kernel, dim3((N + 3) / 4), dim3(256), 0, stream, hl1, as1, ad1, mx1, inv1, row_ptr, col, b1, h1, N);

  // layer 2
  hipLaunchKernelGGL(gemm2_kernel, dim3((N + 127) / 128), dim3(256), 0, stream, h1, W2, h2, N);
  hipLaunchKernelGGL(alpha2_kernel, dim3((N + 7) / 8), dim3(256), 0, stream, h2, asrc2, adst2, as2, ad2, N);
  hipLaunchKernelGGL(stats2_kernel, dim3((N + 255) / 256), dim3(256), 0, stream, as2, ad2, row_ptr, col, mx2, inv2, N);
  hipLaunchKernelGGL(agg2_kernel, dim3((N + 3) / 4), dim3(256), 0, stream, h2, as2, ad2, mx2, inv2, row_ptr, col, b2, out, N);
}

// Round 14
// 398.213 us; speedup vs baseline: 2.1120x; 1.0319x over previous
//
#include <hip/hip_runtime.h>
#include <hip/hip_fp16.h>
#include <math.h>

// Problem constants (from reference): F_in=256, H=4, HID=64 -> D1=256, OUT=32
#define FIN  256
#define D1   256
#define NHEAD 4
#define HIDC 64
#define DOUT 32
#define NSLOPE 0.2f
#define SCHUNK 2048   // scan: elements per block (256 thr x 8)

typedef __attribute__((ext_vector_type(8))) short short8v;     // 8 bf16 bits
typedef __attribute__((ext_vector_type(8))) _Float16 half8v;   // 8 fp16
typedef __attribute__((ext_vector_type(4))) float f32x4;       // MFMA acc

__device__ __forceinline__ float lrelu(float x) { return x >= 0.f ? x : NSLOPE * x; }

// round-to-nearest-even fp32 -> bf16 split: x ~= hi + lo (both bf16)
__device__ __forceinline__ void bf16split(float x, unsigned short& h, unsigned short& l) {
  unsigned u = __float_as_uint(x);
  unsigned uh = (u + 0x7fffu + ((u >> 16) & 1u)) & 0xffff0000u;
  h = (unsigned short)(uh >> 16);
  float r = x - __uint_as_float(uh);
  unsigned ur = __float_as_uint(r);
  l = (unsigned short)((ur + 0x7fffu + ((ur >> 16) & 1u)) >> 16);
}

// ---------------- CSR construction ----------------
__global__ void zero2_kernel(int* __restrict__ a, int* __restrict__ b, int n) {
  int i = blockIdx.x * blockDim.x + threadIdx.x;
  if (i < n) { a[i] = 0; b[i] = 0; }
}

__global__ void count_kernel(const int* __restrict__ src, const int* __restrict__ dst,
                             int* __restrict__ deg, int E, int N) {
  int i = blockIdx.x * blockDim.x + threadIdx.x;
  if (i < E) {
    atomicAdd(&deg[dst[i]], 1);
  } else if (i < E + N) {
    atomicAdd(&deg[i - E], 1);   // self-loop
  }
}

// ---- hierarchical scan ----
__global__ __launch_bounds__(256) void scan1_kernel(const int* __restrict__ deg,
                                                    int* __restrict__ bsum, int N) {
  int b = blockIdx.x, t = threadIdx.x;
  int base = b * SCHUNK + t * 8;
  int s = 0;
  if (base + 8 <= N) {
    int4 a = *(const int4*)&deg[base];
    int4 c = *(const int4*)&deg[base + 4];
    s = a.x + a.y + a.z + a.w + c.x + c.y + c.z + c.w;
  } else {
#pragma unroll
    for (int i = 0; i < 8; ++i) if (base + i < N) s += deg[base + i];
  }
  int lane = t & 63, w = t >> 6;
#pragma unroll
  for (int off = 32; off >= 1; off >>= 1) s += __shfl_down(s, off);
  __shared__ int sh[4];
  if (lane == 0) sh[w] = s;
  __syncthreads();
  if (t == 0) bsum[b] = sh[0] + sh[1] + sh[2] + sh[3];
}

__global__ __launch_bounds__(1024) void scan2_kernel(int* __restrict__ bsum, int nb) {
  __shared__ int sh[1024];
  int t = threadIdx.x;
  sh[t] = (t < nb) ? bsum[t] : 0;
  __syncthreads();
  for (int off = 1; off < 1024; off <<= 1) {
    int u = (t >= off) ? sh[t - off] : 0;
    __syncthreads();
    sh[t] += u;
    __syncthreads();
  }
  if (t < nb) bsum[t] = sh[t];
}

__global__ __launch_bounds__(256) void scan3_kernel(const int* __restrict__ deg,
                                                    const int* __restrict__ bsum,
                                                    int* __restrict__ row_ptr, int N) {
  int b = blockIdx.x, t = threadIdx.x;
  int base = b * SCHUNK + t * 8;
  int vals[8];
  if (base + 8 <= N) {
    int4 a = *(const int4*)&deg[base];
    int4 c = *(const int4*)&deg[base + 4];
    vals[0] = a.x; vals[1] = a.y; vals[2] = a.z; vals[3] = a.w;
    vals[4] = c.x; vals[5] = c.y; vals[6] = c.z; vals[7] = c.w;
  } else {
#pragma unroll
    for (int i = 0; i < 8; ++i) vals[i] = (base + i < N) ? deg[base + i] : 0;
  }
  int s = 0;
#pragma unroll
  for (int i = 0; i < 8; ++i) { s += vals[i]; vals[i] = s; }
  int lane = t & 63, w = t >> 6;
  int inc = s;
#pragma unroll
  for (int off = 1; off < 64; off <<= 1) {
    int u = __shfl_up(inc, off);
    if (lane >= off) inc += u;
  }
  __shared__ int wsum[4];
  if (lane == 63) wsum[w] = inc;
  __syncthreads();
  int woff = 0;
#pragma unroll
  for (int i = 0; i < 4; ++i) if (i < w) woff += wsum[i];
  int excl = woff + inc - s;
  int offbase = (b ? bsum[b - 1] : 0) + excl;
#pragma unroll
  for (int i = 0; i < 8; ++i) {
    int idx = base + i;
    if (idx < N) row_ptr[idx + 1] = offbase + vals[i];
  }
  if (b == 0 && t == 0) row_ptr[0] = 0;
}

__global__ void scatter_kernel(const int* __restrict__ src, const int* __restrict__ dst,
                               const int* __restrict__ row_ptr, int* __restrict__ cur,
                               int* __restrict__ col, int E, int N) {
  int i = blockIdx.x * blockDim.x + threadIdx.x;
  int s, d;
  if (i < E) { s = src[i]; d = dst[i]; }
  else if (i < E + N) { s = i - E; d = i - E; }
  else return;
  int pos = row_ptr[d] + atomicAdd(&cur[d], 1);
  col[pos] = s;
}

// ---------------- weight prep: W1 split+transpose (bf16), W2 fp16 transpose ----------------
__global__ __launch_bounds__(256) void splitW1_kernel(const float* __restrict__ W1,
                                                      unsigned short* __restrict__ Wt_hi,
                                                      unsigned short* __restrict__ Wt_lo) {
  int t = blockIdx.x * 256 + threadIdx.x;   // 65536 threads
  int c = t >> 8, k = t & 255;
  float x = W1[(size_t)k * D1 + c];
  unsigned short h, l;
  bf16split(x, h, l);
  Wt_hi[(size_t)c * FIN + k] = h;
  Wt_lo[(size_t)c * FIN + k] = l;
}

__global__ __launch_bounds__(256) void splitW2_kernel(const float* __restrict__ W2,
                                                      __half* __restrict__ W2t) {
  int t = blockIdx.x * 256 + threadIdx.x;   // 8192 threads
  int c = t >> 8, k = t & 255;
  W2t[t] = __float2half(W2[(size_t)k * DOUT + c]);   // W2t[c][k]
}

// ---------------- GEMM1 (MFMA split-bf16): [N,256] @ [256,256] -> fp16 ----------------
__global__ __launch_bounds__(256) void gemm1_kernel(const float* __restrict__ A,
                                                    const unsigned short* __restrict__ Bt_hi,
                                                    const unsigned short* __restrict__ Bt_lo,
                                                    __half* __restrict__ C, int N) {
  __shared__ unsigned short As_hi[64][40];
  __shared__ unsigned short As_lo[64][40];
  __shared__ unsigned short Bs_hi[256][40];
  __shared__ unsigned short Bs_lo[256][40];
  int t = threadIdx.x;
  int row0 = blockIdx.x * 64;
  int lane = t & 63;
  int col0 = (t >> 6) * 64;
  int frow = lane & 15;
  int fk8  = lane >> 4;

  f32x4 acc[4][4];
#pragma unroll
  for (int i = 0; i < 4; ++i)
#pragma unroll
    for (int j = 0; j < 4; ++j)
#pragma unroll
      for (int q = 0; q < 4; ++q) acc[i][j][q] = 0.f;

  for (int k0 = 0; k0 < 256; k0 += 32) {
    {
      int r = t >> 3;
      int kk = (t & 7) * 4;
#pragma unroll
      for (int rep = 0; rep < 2; ++rep) {
        int rr = r + rep * 32;
        int gr = row0 + rr;
        float4 v = {0.f, 0.f, 0.f, 0.f};
        if (gr < N) v = *(const float4*)&A[(size_t)gr * FIN + k0 + kk];
        unsigned short h0, l0, h1, l1, h2, l2, h3, l3;
        bf16split(v.x, h0, l0); bf16split(v.y, h1, l1);
        bf16split(v.z, h2, l2); bf16split(v.w, h3, l3);
        ushort4 vh = {h0, h1, h2, h3};
        ushort4 vl = {l0, l1, l2, l3};
        *(ushort4*)&As_hi[rr][kk] = vh;
        *(ushort4*)&As_lo[rr][kk] = vl;
      }
    }
    {
#pragma unroll
      for (int q = 0; q < 4; ++q) {
        int4 vh = *(const int4*)&Bt_hi[(size_t)t * FIN + k0 + q * 8];
        int4 vl = *(const int4*)&Bt_lo[(size_t)t * FIN + k0 + q * 8];
        *(int4*)&Bs_hi[t][q * 8] = vh;
        *(int4*)&Bs_lo[t][q * 8] = vl;
      }
    }
    __syncthreads();
    short8v bh[4], bl[4];
#pragma unroll
    for (int ct = 0; ct < 4; ++ct) {
      bh[ct] = *(const short8v*)&Bs_hi[col0 + ct * 16 + frow][fk8 * 8];
      bl[ct] = *(const short8v*)&Bs_lo[col0 + ct * 16 + frow][fk8 * 8];
    }
#pragma unroll
    for (int rt = 0; rt < 4; ++rt) {
      short8v ah = *(const short8v*)&As_hi[rt * 16 + frow][fk8 * 8];
      short8v al = *(const short8v*)&As_lo[rt * 16 + frow][fk8 * 8];
#pragma unroll
      for (int ct = 0; ct < 4; ++ct) {
        acc[rt][ct] = __builtin_amdgcn_mfma_f32_16x16x32_bf16(ah, bh[ct], acc[rt][ct], 0, 0, 0);
        acc[rt][ct] = __builtin_amdgcn_mfma_f32_16x16x32_bf16(ah, bl[ct], acc[rt][ct], 0, 0, 0);
        acc[rt][ct] = __builtin_amdgcn_mfma_f32_16x16x32_bf16(al, bh[ct], acc[rt][ct], 0, 0, 0);
      }
    }
    __syncthreads();
  }
#pragma unroll
  for (int rt = 0; rt < 4; ++rt) {
#pragma unroll
    for (int i = 0; i < 4; ++i) {
      int gr = row0 + rt * 16 + fk8 * 4 + i;
      if (gr < N) {
#pragma unroll
        for (int ct = 0; ct < 4; ++ct)
          C[(size_t)gr * D1 + col0 + ct * 16 + frow] = __float2half(acc[rt][ct][i]);
      }
    }
  }
}

// ---------------- alpha1: per-node dot with att vectors (fp16 h) ----------------
__global__ __launch_bounds__(256) void alpha1_kernel(const __half* __restrict__ h,
                                                     const float* __restrict__ a_src,
                                                     const float* __restrict__ a_dst,
                                                     float* __restrict__ as,
                                                     float* __restrict__ ad, int N) {
  int wid = (blockIdx.x * blockDim.x + threadIdx.x) >> 6;
  if (wid >= N) return;
  int lane = threadIdx.x & 63;
  int2 r = *(const int2*)&h[(size_t)wid * D1 + lane * 4];
  float2 f01 = __half22float2(*(__half2*)&r.x);
  float2 f23 = __half22float2(*(__half2*)&r.y);
  float4 s4 = *(const float4*)&a_src[lane * 4];
  float4 d4 = *(const float4*)&a_dst[lane * 4];
  float ps = f01.x * s4.x + f01.y * s4.y + f23.x * s4.z + f23.y * s4.w;
  float pd = f01.x * d4.x + f01.y * d4.y + f23.x * d4.z + f23.y * d4.w;
#pragma unroll
  for (int off = 8; off >= 1; off >>= 1) {
    ps += __shfl_xor(ps, off);
    pd += __shfl_xor(pd, off);
  }
  int hh = lane >> 4;
  if ((lane & 15) == 0) { as[wid * 4 + hh] = ps; ad[wid * 4 + hh] = pd; }
}

// ---------------- stats1: per-(node,head) stats + per-edge weights ----------------
__global__ __launch_bounds__(256) void stats1_kernel(const float* __restrict__ as1,
                                                     const float* __restrict__ ad1,
                                                     const int* __restrict__ row_ptr,
                                                     const int* __restrict__ col,
                                                     float* __restrict__ wbuf, int N) {
  int t = blockIdx.x * blockDim.x + threadIdx.x;
  if (t >= N * 4) return;
  int n = t >> 2, h = t & 3;
  int beg = row_ptr[n];
  int deg = row_ptr[n + 1] - beg;
  float adh = ad1[t];
  float m = -INFINITY, s = 0.f;
  int cn = col[beg];
  for (int j = 0; j < deg; ++j) {
    int c = cn;
    if (j + 1 < deg) cn = col[beg + j + 1];
    float e = lrelu(as1[(size_t)c * 4 + h] + adh);
    float nm = fmaxf(m, e);
    s = s * expf(m - nm) + expf(e - nm);
    m = nm;
  }
  float inv = 1.f / (s + 1e-16f);
  // second pass: normalized weight per edge (L2-warm re-gather)
  cn = col[beg];
  for (int j = 0; j < deg; ++j) {
    int c = cn;
    if (j + 1 < deg) cn = col[beg + j + 1];
    float e = lrelu(as1[(size_t)c * 4 + h] + adh);
    wbuf[(size_t)(beg + j) * 4 + h] = expf(e - m) * inv;
  }
}

// ---------------- agg1: weighted aggregate, fp16 gather + precomputed weights ----------------
__global__ __launch_bounds__(256) void agg1_kernel(const __half* __restrict__ hl,
                                                   const float* __restrict__ wbuf,
                                                   const int* __restrict__ row_ptr,
                                                   const int* __restrict__ col,
                                                   const float* __restrict__ b1,
                                                   __half* __restrict__ h1, int N) {
  int wid = (blockIdx.x * blockDim.x + threadIdx.x) >> 6;
  if (wid >= N) return;
  int lane = threadIdx.x & 63;
  int hm = lane >> 4;
  int beg = row_ptr[wid];
  int deg = row_ptr[wid + 1] - beg;
  float4 acc = {0.f, 0.f, 0.f, 0.f};
  int j = 0;
  for (; j + 4 <= deg; j += 4) {
    int s0 = col[beg + j + 0];
    int s1 = col[beg + j + 1];
    int s2 = col[beg + j + 2];
    int s3 = col[beg + j + 3];
    float w0 = wbuf[(size_t)(beg + j + 0) * 4 + hm];
    float w1 = wbuf[(size_t)(beg + j + 1) * 4 + hm];
    float w2 = wbuf[(size_t)(beg + j + 2) * 4 + hm];
    float w3 = wbuf[(size_t)(beg + j + 3) * 4 + hm];
    int2 r0 = *(const int2*)&hl[(size_t)s0 * D1 + lane * 4];
    int2 r1 = *(const int2*)&hl[(size_t)s1 * D1 + lane * 4];
    int2 r2 = *(const int2*)&hl[(size_t)s2 * D1 + lane * 4];
    int2 r3 = *(const int2*)&hl[(size_t)s3 * D1 + lane * 4];
    float2 u, v;
    u = __half22float2(*(__half2*)&r0.x); v = __half22float2(*(__half2*)&r0.y);
    acc.x = fmaf(w0, u.x, acc.x); acc.y = fmaf(w0, u.y, acc.y);
    acc.z = fmaf(w0, v.x, acc.z); acc.w = fmaf(w0, v.y, acc.w);
    u = __half22float2(*(__half2*)&r1.x); v = __half22float2(*(__half2*)&r1.y);
    acc.x = fmaf(w1, u.x, acc.x); acc.y = fmaf(w1, u.y, acc.y);
    acc.z = fmaf(w1, v.x, acc.z); acc.w = fmaf(w1, v.y, acc.w);
    u = __half22float2(*(__half2*)&r2.x); v = __half22float2(*(__half2*)&r2.y);
    acc.x = fmaf(w2, u.x, acc.x); acc.y = fmaf(w2, u.y, acc.y);
    acc.z = fmaf(w2, v.x, acc.z); acc.w = fmaf(w2, v.y, acc.w);
    u = __half22float2(*(__half2*)&r3.x); v = __half22float2(*(__half2*)&r3.y);
    acc.x = fmaf(w3, u.x, acc.x); acc.y = fmaf(w3, u.y, acc.y);
    acc.z = fmaf(w3, v.x, acc.z); acc.w = fmaf(w3, v.y, acc.w);
  }
  for (; j < deg; ++j) {
    int s0 = col[beg + j];
    float w0 = wbuf[(size_t)(beg + j) * 4 + hm];
    int2 r0 = *(const int2*)&hl[(size_t)s0 * D1 + lane * 4];
    float2 u = __half22float2(*(__half2*)&r0.x);
    float2 v = __half22float2(*(__half2*)&r0.y);
    acc.x = fmaf(w0, u.x, acc.x); acc.y = fmaf(w0, u.y, acc.y);
    acc.z = fmaf(w0, v.x, acc.z); acc.w = fmaf(w0, v.y, acc.w);
  }
  float4 bb = *(const float4*)&b1[lane * 4];
  __half2 p0 = __floats2half2_rn(fmaxf(acc.x + bb.x, 0.f), fmaxf(acc.y + bb.y, 0.f));
  __half2 p1 = __floats2half2_rn(fmaxf(acc.z + bb.z, 0.f), fmaxf(acc.w + bb.w, 0.f));
  int2 pk;
  pk.x = *(int*)&p0;
  pk.y = *(int*)&p1;
  *(int2*)&h1[(size_t)wid * D1 + lane * 4] = pk;
}

// ---------------- GEMM2 (MFMA f16): fp16 [N,256] @ [256,32] -> fp16 [N,32] ----------------
// LDS-free: B-frags (whole W2t) in registers; A-frags streamed from global.
// Wave-tile = 32 rows x 32 cols; block = 4 waves = 128 rows.
__global__ __launch_bounds__(256) void gemm2_kernel(const __half* __restrict__ A,
                                                    const __half* __restrict__ Bt,
                                                    __half* __restrict__ C, int N) {
  int t = threadIdx.x;
  int lane = t & 63;
  int frow = lane & 15, fk8 = lane >> 4;
  int row0 = (blockIdx.x * 4 + (t >> 6)) * 32;
  if (row0 >= N) return;
  half8v bf[8][2];
#pragma unroll
  for (int k8 = 0; k8 < 8; ++k8)
#pragma unroll
    for (int ct = 0; ct < 2; ++ct)
      bf[k8][ct] = *(const half8v*)&Bt[(size_t)(ct * 16 + frow) * 256 + k8 * 32 + fk8 * 8];
  f32x4 acc[2][2];
#pragma unroll
  for (int rt = 0; rt < 2; ++rt)
#pragma unroll
    for (int ct = 0; ct < 2; ++ct)
#pragma unroll
      for (int q = 0; q < 4; ++q) acc[rt][ct][q] = 0.f;
#pragma unroll
  for (int k8 = 0; k8 < 8; ++k8) {
#pragma unroll
    for (int rt = 0; rt < 2; ++rt) {
      int gr = row0 + rt * 16 + frow;
      if (gr >= N) gr = N - 1;                 // clamp; stores guarded
      half8v af = *(const half8v*)&A[(size_t)gr * D1 + k8 * 32 + fk8 * 8];
#pragma unroll
      for (int ct = 0; ct < 2; ++ct)
        acc[rt][ct] = __builtin_amdgcn_mfma_f32_16x16x32_f16(af, bf[k8][ct], acc[rt][ct], 0, 0, 0);
    }
  }
#pragma unroll
  for (int rt = 0; rt < 2; ++rt)
#pragma unroll
    for (int i = 0; i < 4; ++i) {
      int gr = row0 + rt * 16 + fk8 * 4 + i;
      if (gr < N) {
#pragma unroll
        for (int ct = 0; ct < 2; ++ct)
          C[(size_t)gr * DOUT + ct * 16 + frow] = __float2half(acc[rt][ct][i]);
      }
    }
}

// ---------------- alpha2: one wave handles two nodes (fp16 h2) ----------------
__global__ __launch_bounds__(256) void alpha2_kernel(const __half* __restrict__ h2,
                                                     const float* __restrict__ a_src,
                                                     const float* __restrict__ a_dst,
                                                     float* __restrict__ as,
                                                     float* __restrict__ ad, int N) {
  int wid = (blockIdx.x * blockDim.x + threadIdx.x) >> 6;
  int lane = threadIdx.x & 63;
  int n = wid * 2 + (lane >> 5);
  int c = lane & 31;
  float v = (n < N) ? __half2float(h2[(size_t)n * DOUT + c]) : 0.f;
  float ps = v * a_src[c];
  float pd = v * a_dst[c];
#pragma unroll
  for (int off = 16; off >= 1; off >>= 1) {
    ps += __shfl_xor(ps, off);
    pd += __shfl_xor(pd, off);
  }
  if (c == 0 && n < N) { as[n] = ps; ad[n] = pd; }
}

// ---------------- stats2: per-node stats + per-edge weights (H=1) ----------------
__global__ __launch_bounds__(256) void stats2_kernel(const float* __restrict__ as2,
                                                     const float* __restrict__ ad2,
                                                     const int* __restrict__ row_ptr,
                                                     const int* __restrict__ col,
                                                     float* __restrict__ wbuf2, int N) {
  int n = blockIdx.x * blockDim.x + threadIdx.x;
  if (n >= N) return;
  int beg = row_ptr[n];
  int deg = row_ptr[n + 1] - beg;
  float ad = ad2[n];
  float m = -INFINITY, s = 0.f;
  int cn = col[beg];
  for (int j = 0; j < deg; ++j) {
    int c = cn;
    if (j + 1 < deg) cn = col[beg + j + 1];
    float e = lrelu(as2[c] + ad);
    float nm = fmaxf(m, e);
    s = s * expf(m - nm) + expf(e - nm);
    m = nm;
  }
  float inv = 1.f / (s + 1e-16f);
  cn = col[beg];
  for (int j = 0; j < deg; ++j) {
    int c = cn;
    if (j + 1 < deg) cn = col[beg + j + 1];
    wbuf2[beg + j] = expf(lrelu(as2[c] + ad) - m) * inv;
  }
}

// ---------------- agg2: weighted aggregate (H=1, C=32), precomputed weights ----------------
__global__ __launch_bounds__(256) void agg2_kernel(const __half* __restrict__ h2,
                                                   const float* __restrict__ wbuf2,
                                                   const int* __restrict__ row_ptr,
                                                   const int* __restrict__ col,
                                                   const float* __restrict__ b2,
                                                   float* __restrict__ out, int N) {
  int wid = (blockIdx.x * blockDim.x + threadIdx.x) >> 6;
  if (wid >= N) return;
  int lane = threadIdx.x & 63;
  int c = lane & 31;
  int beg = row_ptr[wid];
  int deg = row_ptr[wid + 1] - beg;
  float acc = 0.f;
  int j = 0;
  for (; j + 4 <= deg; j += 4) {
    int s0 = col[beg + j + 0];
    int s1 = col[beg + j + 1];
    int s2 = col[beg + j + 2];
    int s3 = col[beg + j + 3];
    float w0 = wbuf2[beg + j + 0];
    float w1 = wbuf2[beg + j + 1];
    float w2 = wbuf2[beg + j + 2];
    float w3 = wbuf2[beg + j + 3];
    float v0 = __half2float(h2[(size_t)s0 * DOUT + c]);
    float v1 = __half2float(h2[(size_t)s1 * DOUT + c]);
    float v2 = __half2float(h2[(size_t)s2 * DOUT + c]);
    float v3 = __half2float(h2[(size_t)s3 * DOUT + c]);
    acc = fmaf(w0, v0, acc);
    acc = fmaf(w1, v1, acc);
    acc = fmaf(w2, v2, acc);
    acc = fmaf(w3, v3, acc);
  }
  for (; j < deg; ++j) {
    int s0 = col[beg + j];
    float w0 = wbuf2[beg + j];
    acc = fmaf(w0, __half2float(h2[(size_t)s0 * DOUT + c]), acc);
  }
  if (lane < 32) out[(size_t)wid * DOUT + c] = acc + b2[c];
}

// ---------------- launch ----------------
extern "C" void kernel_launch(void* const* d_in, const int* in_sizes, int n_in,
                              void* d_out, int out_size, void* d_ws, size_t ws_size,
                              hipStream_t stream) {
  const float* x     = (const float*)d_in[0];
  const int*   ei    = (const int*)d_in[1];
  const float* W1    = (const float*)d_in[2];
  const float* asrc1 = (const float*)d_in[3];
  const float* adst1 = (const float*)d_in[4];
  const float* b1    = (const float*)d_in[5];
  const float* W2    = (const float*)d_in[6];
  const float* asrc2 = (const float*)d_in[7];
  const float* adst2 = (const float*)d_in[8];
  const float* b2    = (const float*)d_in[9];

  const int N = in_sizes[0] / FIN;
  const int E = in_sizes[1] / 2;
  const int ET = E + N;
  const int* src = ei;
  const int* dst = ei + E;
  const int NB = (N + SCHUNK - 1) / SCHUNK;

  char* base = (char*)d_ws;
  size_t off = 0;
  auto alloc = [&](size_t bytes) -> void* {
    void* p = base + off;
    off = (off + bytes + 255) & ~(size_t)255;
    return p;
  };
  int* row_ptr = (int*)alloc((size_t)(N + 1) * 4);
  int* deg     = (int*)alloc((size_t)N * 4);
  int* cur     = (int*)alloc((size_t)N * 4);
  int* col     = (int*)alloc((size_t)ET * 4);
  int* bsum    = (int*)alloc((size_t)1024 * 4);
  float* as1   = (float*)alloc((size_t)N * 4 * 4);
  float* ad1   = (float*)alloc((size_t)N * 4 * 4);
  float* as2   = (float*)alloc((size_t)N * 4);
  float* ad2   = (float*)alloc((size_t)N * 4);
  float* wbuf1 = (float*)alloc((size_t)ET * 4 * 4);
  float* wbuf2 = (float*)alloc((size_t)ET * 4);
  unsigned short* Wt_hi = (unsigned short*)alloc((size_t)FIN * D1 * 2);
  unsigned short* Wt_lo = (unsigned short*)alloc((size_t)FIN * D1 * 2);
  __half* W2t  = (__half*)alloc((size_t)D1 * DOUT * 2);
  __half* hl1  = (__half*)alloc((size_t)N * D1 * 2);   // fp16 gather source L1
  __half* h1   = (__half*)alloc((size_t)N * D1 * 2);   // fp16, streamed by gemm2
  __half* h2   = hl1;   // reuse: hl1 dead after agg1
  float* out   = (float*)d_out;

  // CSR build + weight prep
  hipLaunchKernelGGL(zero2_kernel, dim3((N + 255) / 256), dim3(256), 0, stream, deg, cur, N);
  hipLaunchKernelGGL(count_kernel, dim3((ET + 255) / 256), dim3(256), 0, stream, src, dst, deg, E, N);
  hipLaunchKernelGGL(splitW1_kernel, dim3(FIN * D1 / 256), dim3(256), 0, stream, W1, Wt_hi, Wt_lo);
  hipLaunchKernelGGL(splitW2_kernel, dim3(D1 * DOUT / 256), dim3(256), 0, stream, W2, W2t);
  hipLaunchKernelGGL(scan1_kernel, dim3(NB), dim3(256), 0, stream, deg, bsum, N);
  hipLaunchKernelGGL(scan2_kernel, dim3(1), dim3(1024), 0, stream, bsum, NB);
  hipLaunchKernelGGL(scan3_kernel, dim3(NB), dim3(256), 0, stream, deg, bsum, row_ptr, N);
  hipLaunchKernelGGL(scatter_kernel, dim3((ET + 255) / 256), dim3(256), 0, stream, src, dst, row_ptr, cur, col, E, N);

  // layer 1
  hipLaunchKernelGGL(gemm1_kernel, dim3((N + 63) / 64), dim3(256), 0, stream, x, Wt_hi, Wt_lo, hl1, N);
  hipLaunchKernelGGL(alpha1_kernel, dim3((N + 3) / 4), dim3(256), 0, stream, hl1, asrc1, adst1, as1, ad1, N);
  hipLaunchKernelGGL(stats1_kernel, dim3((N * 4 + 255) / 256), dim3(256), 0, stream, as1, ad1, row_ptr, col, wbuf1, N);
  hipLaunchKernelGGL(agg1_kernel, dim3((N + 3) / 4), dim3(256), 0, stream, hl1, wbuf1, row_ptr, col, b1, h1, N);

  // layer 2
  hipLaunchKernelGGL(gemm2_kernel, dim3((N / 32 + 4) / 4), dim3(256), 0, stream, h1, W2t, h2, N);
  hipLaunchKernelGGL(alpha2_kernel, dim3((N + 7) / 8), dim3(256), 0, stream, h2, asrc2, adst2, as2, ad2, N);
  hipLaunchKernelGGL(stats2_kernel, dim3((N + 255) / 256), dim3(256), 0, stream, as2, ad2, row_ptr, col, wbuf2, N);
  hipLaunchKernelGGL(agg2_kernel, dim3((N + 3) / 4), dim3(256), 0, stream, h2, wbuf2, row_ptr, col, b2, out, N);
}